// Round 8
// baseline (961.445 us; speedup 1.0000x reference)
//
#include <hip/hip_runtime.h>
#include <hip/hip_bf16.h>
#include <math.h>

constexpr int T_ = 1024;
constexpr int HDIM = 2048;
constexpr int NH = 16;
constexpr int QKD = 96;
constexpr int VD = 64;
constexpr int MAXTILES = 24;
constexpr float EPSF = 1e-6f;

using f32x4 = __attribute__((ext_vector_type(4))) float;
using s16x8 = __attribute__((ext_vector_type(8))) short;
using s16x4 = __attribute__((ext_vector_type(4))) short;

// ---------------- workspace layout (round-6 verified; float offsets) ----------------
constexpr size_t OF_CATH  = 0;                 // bf16 T*4096
constexpr size_t OF_CATL  = 2097152;
constexpr size_t OF_GATH  = 0;                 // f32 2048*2048 (alias cat planes; disjoint lifetime)
constexpr size_t OF_X0    = 4194304;           // f32 T*2048
constexpr size_t OF_H2    = 6291456;           // f32 T*2048
constexpr size_t OF_HH    = 8388608;           // bf16 T*2048
constexpr size_t OF_HL    = 9437184;
constexpr size_t OF_SHO   = 8388608;           // f32 T*2048 (alias h planes)
constexpr size_t OF_QRAW  = 10485760;          // f32 T*512
constexpr size_t OF_QBUF  = 11010048;          // f32 T*1536
constexpr size_t OF_KVA   = 12582912;          // f32 T*288
constexpr size_t OF_KVBUF = 12877824;          // f32 T*2048
constexpr size_t OF_MD    = 10485760;          // f32 2048*2048 (alias qraw..kvbuf)
constexpr size_t OF_QAH   = 14974976;          // bf16 T*512
constexpr size_t OF_QAL   = 15237120;
constexpr size_t OF_KVCNH = 15499264;          // bf16 T*256
constexpr size_t OF_KVCNL = 15630336;
constexpr size_t OF_QFH   = 15761408;          // bf16 T*1536
constexpr size_t OF_QFL   = 16547840;
constexpr size_t OF_KFH   = 17334272;
constexpr size_t OF_KFL   = 18120704;
constexpr size_t OF_VBH   = 18907136;          // bf16 T*1024
constexpr size_t OF_VBL   = 19431424;
constexpr size_t OF_MG    = 15761408;          // f32 2048*1024 (alias qf/kf planes)
constexpr size_t OF_MU    = 17858560;          // f32 2048*1024 (alias kf/vb planes)
constexpr size_t OF_OBH   = 19955712;          // bf16 T*1024
constexpr size_t OF_OBL   = 20480000;
constexpr size_t OF_ATT   = 21004288;          // f32 T*2048
constexpr size_t OF_SG    = 21004288;          // f32 T*1024 (alias att)
constexpr size_t OF_SU    = 22052864;          // f32 T*1024
constexpr size_t OF_H2BF  = 23101440;          // bf16 T*2048
constexpr size_t OF_SGACT = 24150016;          // bf16 T*1024
constexpr size_t OF_ROUT  = 24674304;          // ints
// weight planes (bf16)
constexpr size_t OF_EHTH  = 24682752;          // [2048][4096]
constexpr size_t OF_EHTL  = 28877056;
constexpr size_t OF_QATH  = 33071360;          // [512][2048]
constexpr size_t OF_QATL  = 33595648;
constexpr size_t OF_QBTH  = 34119936;          // [1536][512]
constexpr size_t OF_QBTL  = 34513152;
constexpr size_t OF_KVATH = 34906368;          // [384][2048] (288 used, zero-padded)
constexpr size_t OF_KVATL = 35234048;
constexpr size_t OF_KVBTH = 35561728;          // [2048][256]
constexpr size_t OF_KVBTL = 35823872;
constexpr size_t OF_OWTH  = 36086016;          // [2048][1024]
constexpr size_t OF_OWTL  = 37134592;
constexpr size_t OF_SHGT  = 38183168;          // [1024][2048]
constexpr size_t OF_SHUT  = 39231744;
constexpr size_t OF_SHDT  = 40280320;          // [2048][1024]

// ---------------- helpers ----------------
__device__ __forceinline__ short f2bf(float f) {
    union { float f; unsigned u; } x; x.f = f;
    unsigned r = x.u + 0x7fffu + ((x.u >> 16) & 1u);
    return (short)(r >> 16);
}
__device__ __forceinline__ float bf2f(short h) {
    union { unsigned u; float f; } x; x.u = ((unsigned)(unsigned short)h) << 16; return x.f;
}
// LDS swizzle: row stride 64 shorts (128 B = 8 chunks of 16 B); chunk ^= row&7
__device__ __forceinline__ int swz(int r, int k) {
    return (r << 6) + ((((k >> 3) ^ (r & 7)) << 3) | (k & 7));
}

__device__ __forceinline__ float block_sum(float v) {
    __shared__ float sbuf[9];
    int lane = threadIdx.x & 63;
    int wid  = threadIdx.x >> 6;
#pragma unroll
    for (int off = 32; off > 0; off >>= 1) v += __shfl_down(v, off);
    __syncthreads();
    if (lane == 0) sbuf[wid] = v;
    __syncthreads();
    if (threadIdx.x == 0) {
        float s = 0.f;
        int nw = blockDim.x >> 6;
        for (int i = 0; i < nw; i++) s += sbuf[i];
        sbuf[8] = s;
    }
    __syncthreads();
    return sbuf[8];
}

// ---------------- weight transpose + split: W[K][N] f32 -> [Npad][K] bf16 planes ----------------
__global__ void transpose_split_kernel(const float* __restrict__ W, short* __restrict__ Whi,
                                       short* __restrict__ Wlo, int K, int N, int split) {
    __shared__ float tile[64][65];
    int k0 = blockIdx.x * 64, n0 = blockIdx.y * 64;
    int tn = threadIdx.x & 63;
    int tk4 = threadIdx.x >> 6;
#pragma unroll 4
    for (int i = 0; i < 16; i++) {
        int kk = tk4 * 16 + i;
        int gn = n0 + tn;
        tile[kk][tn] = (gn < N) ? W[(size_t)(k0 + kk) * N + gn] : 0.f;
    }
    __syncthreads();
    int on = threadIdx.x >> 2;
    int oc = threadIdx.x & 3;
#pragma unroll 4
    for (int i = 0; i < 16; i++) {
        int kk = oc * 16 + i;
        float v = tile[kk][on];
        short hh = f2bf(v);
        size_t o = (size_t)(n0 + on) * K + k0 + kk;
        Whi[o] = hh;
        if (split) Wlo[o] = f2bf(v - bf2f(hh));
    }
}

// ---------------- embedding + rmsnorm + concat -> split planes ----------------
__global__ void embed_cat_kernel(const int* __restrict__ ids, const float* __restrict__ embed,
                                 const float* __restrict__ enorm, const float* __restrict__ prev,
                                 const float* __restrict__ hnorm, short* __restrict__ ch,
                                 short* __restrict__ cl) {
    int t = blockIdx.x;
    const float* e = embed + (size_t)ids[t] * HDIM;
    float ss = 0.f;
    for (int i = threadIdx.x; i < HDIM; i += blockDim.x) { float v = e[i]; ss += v * v; }
    float r = rsqrtf(block_sum(ss) / HDIM + EPSF);
    for (int i = threadIdx.x; i < HDIM; i += blockDim.x) {
        float v = e[i] * r * enorm[i];
        short hh = f2bf(v);
        ch[(size_t)t * 4096 + i] = hh;
        cl[(size_t)t * 4096 + i] = f2bf(v - bf2f(hh));
    }
    const float* p = prev + (size_t)t * HDIM;
    ss = 0.f;
    for (int i = threadIdx.x; i < HDIM; i += blockDim.x) { float v = p[i]; ss += v * v; }
    r = rsqrtf(block_sum(ss) / HDIM + EPSF);
    for (int i = threadIdx.x; i < HDIM; i += blockDim.x) {
        float v = p[i] * r * hnorm[i];
        short hh = f2bf(v);
        ch[(size_t)t * 4096 + 2048 + i] = hh;
        cl[(size_t)t * 4096 + 2048 + i] = f2bf(v - bf2f(hh));
    }
}

// ---------------- rmsnorm with optional f32 / hi / lo outputs ----------------
__global__ void rmsnorm_kernel(const float* __restrict__ in, int in_stride, int width,
                               const float* __restrict__ w, float* __restrict__ outf,
                               short* __restrict__ outh, short* __restrict__ outl, int out_stride) {
    int t = blockIdx.x;
    const float* x = in + (size_t)t * in_stride;
    float ss = 0.f;
    for (int i = threadIdx.x; i < width; i += blockDim.x) { float v = x[i]; ss += v * v; }
    float r = rsqrtf(block_sum(ss) / width + EPSF);
    size_t ob = (size_t)t * out_stride;
    for (int i = threadIdx.x; i < width; i += blockDim.x) {
        float v = x[i] * r * w[i];
        if (outf) outf[ob + i] = v;
        if (outh) {
            short hh = f2bf(v);
            outh[ob + i] = hh;
            if (outl) outl[ob + i] = f2bf(v - bf2f(hh));
        }
    }
}

// =====================================================================
// Plane GEMM: C[M][N] f32 = A(planes [M][K]) @ B^T(planes [Npad][K]).
// BM=128 BN=128 BK=64, 4 waves 2x2 (wave tile 64x64), swizzled LDS.
// SPLIT: 3-MFMA (AhBh + AlBh + AhBl) ~fp32 accuracy.
// (ONLY change vs round-6 passing version: BN 64->128.)
// =====================================================================
template<bool SPLIT>
__global__ __launch_bounds__(256) void gemm_planes(const short* __restrict__ Ahi, const short* __restrict__ Alo,
                                                   const short* __restrict__ Bhi, const short* __restrict__ Blo,
                                                   float* __restrict__ C, int M, int N, int K) {
    alignas(16) __shared__ short As[SPLIT ? 2 : 1][128 * 64];
    alignas(16) __shared__ short Bs[SPLIT ? 2 : 1][128 * 64];
    const int tid = threadIdx.x;
    const int lane = tid & 63, wid = tid >> 6;
    const int g = lane >> 4, li = lane & 15;
    const int wm = wid >> 1, wn = wid & 1;
    const int row0 = blockIdx.y * 128, col0 = blockIdx.x * 128;

    f32x4 acc[4][4];
#pragma unroll
    for (int mi = 0; mi < 4; mi++)
#pragma unroll
        for (int ni = 0; ni < 4; ni++)
#pragma unroll
            for (int r = 0; r < 4; r++) acc[mi][ni][r] = 0.f;

    for (int k0 = 0; k0 < K; k0 += 64) {
        // stage A: 1024 chunks (128 rows x 8), 4/thread
#pragma unroll
        for (int i = 0; i < 4; i++) {
            int cid = i * 256 + tid;
            int r = cid >> 3, c = cid & 7;
            *(s16x8*)&As[0][swz(r, c * 8)] = *(const s16x8*)&Ahi[(size_t)(row0 + r) * K + k0 + c * 8];
            if constexpr (SPLIT)
                *(s16x8*)&As[1][swz(r, c * 8)] = *(const s16x8*)&Alo[(size_t)(row0 + r) * K + k0 + c * 8];
        }
        // stage B^T: 1024 chunks (128 rows x 8), 4/thread
#pragma unroll
        for (int i = 0; i < 4; i++) {
            int cid = i * 256 + tid;
            int r = cid >> 3, c = cid & 7;
            *(s16x8*)&Bs[0][swz(r, c * 8)] = *(const s16x8*)&Bhi[(size_t)(col0 + r) * K + k0 + c * 8];
            if constexpr (SPLIT)
                *(s16x8*)&Bs[1][swz(r, c * 8)] = *(const s16x8*)&Blo[(size_t)(col0 + r) * K + k0 + c * 8];
        }
        __syncthreads();
#pragma unroll
        for (int kk = 0; kk < 64; kk += 32) {
            s16x8 ah[4], bh[4];
#pragma unroll
            for (int mi = 0; mi < 4; mi++) ah[mi] = *(const s16x8*)&As[0][swz(wm * 64 + mi * 16 + li, kk + g * 8)];
#pragma unroll
            for (int ni = 0; ni < 4; ni++) bh[ni] = *(const s16x8*)&Bs[0][swz(wn * 64 + ni * 16 + li, kk + g * 8)];
            if constexpr (SPLIT) {
                s16x8 al[4], bl[4];
#pragma unroll
                for (int mi = 0; mi < 4; mi++) al[mi] = *(const s16x8*)&As[1][swz(wm * 64 + mi * 16 + li, kk + g * 8)];
#pragma unroll
                for (int ni = 0; ni < 4; ni++) bl[ni] = *(const s16x8*)&Bs[1][swz(wn * 64 + ni * 16 + li, kk + g * 8)];
#pragma unroll
                for (int mi = 0; mi < 4; mi++)
#pragma unroll
                    for (int ni = 0; ni < 4; ni++) {
                        acc[mi][ni] = __builtin_amdgcn_mfma_f32_16x16x32_bf16(ah[mi], bh[ni], acc[mi][ni], 0, 0, 0);
                        acc[mi][ni] = __builtin_amdgcn_mfma_f32_16x16x32_bf16(al[mi], bh[ni], acc[mi][ni], 0, 0, 0);
                        acc[mi][ni] = __builtin_amdgcn_mfma_f32_16x16x32_bf16(ah[mi], bl[ni], acc[mi][ni], 0, 0, 0);
                    }
            } else {
#pragma unroll
                for (int mi = 0; mi < 4; mi++)
#pragma unroll
                    for (int ni = 0; ni < 4; ni++)
                        acc[mi][ni] = __builtin_amdgcn_mfma_f32_16x16x32_bf16(ah[mi], bh[ni], acc[mi][ni], 0, 0, 0);
            }
        }
        __syncthreads();
    }
#pragma unroll
    for (int mi = 0; mi < 4; mi++)
#pragma unroll
        for (int ni = 0; ni < 4; ni++) {
            int gc = col0 + wn * 64 + ni * 16 + li;
            if (gc < N) {
#pragma unroll
                for (int r = 0; r < 4; r++) {
                    int gr = row0 + wm * 64 + mi * 16 + g * 4 + r;
                    C[(size_t)gr * N + gc] = acc[mi][ni][r];
                }
            }
        }
}

// ---------------- MoE grouped GEMM (round-6 verbatim, proven) ----------------
__global__ __launch_bounds__(256) void moe_gemm_bf16(const float* __restrict__ Abase, const float* __restrict__ Wall,
                                                     float* __restrict__ Cbase, const int4* __restrict__ tilemap,
                                                     int K, int N) {
    int4 tm = tilemap[blockIdx.y];
    int nrows = tm.z;
    if (nrows == 0) return;
    const float* A = Abase + (size_t)tm.y * K;
    float* C = Cbase + (size_t)tm.y * N;
    const float* B = Wall + (size_t)tm.x * K * N;

    alignas(16) __shared__ short As[128][72];
    alignas(16) __shared__ short Bs[64][72];
    const int tid = threadIdx.x;
    const int lane = tid & 63, wid = tid >> 6;
    const int g = lane >> 4, li = lane & 15;
    const int wm = wid >> 1, wn = wid & 1;
    const int col0 = blockIdx.x * 64;

    f32x4 acc[4][2];
#pragma unroll
    for (int mi = 0; mi < 4; mi++)
#pragma unroll
        for (int ni = 0; ni < 2; ni++)
#pragma unroll
            for (int r = 0; r < 4; r++) acc[mi][ni][r] = 0.f;

    const int sar = tid >> 3, sak = (tid & 7) << 3;
    const int skb = (tid >> 4) << 2, snb = (tid & 15) << 2;

    for (int k0 = 0; k0 < K; k0 += 64) {
#pragma unroll
        for (int i = 0; i < 4; i++) {
            int ar = sar + i * 32;
            s16x8 v;
            if (ar < nrows) {
                const float* src = A + (size_t)ar * K + k0 + sak;
                float4 f0 = *(const float4*)src;
                float4 f1 = *(const float4*)(src + 4);
                v[0] = f2bf(f0.x); v[1] = f2bf(f0.y); v[2] = f2bf(f0.z); v[3] = f2bf(f0.w);
                v[4] = f2bf(f1.x); v[5] = f2bf(f1.y); v[6] = f2bf(f1.z); v[7] = f2bf(f1.w);
            } else {
#pragma unroll
                for (int j = 0; j < 8; j++) v[j] = 0;
            }
            *(s16x8*)&As[ar][sak] = v;
        }
        {
            float4 r4[4];
#pragma unroll
            for (int kk = 0; kk < 4; kk++)
                r4[kk] = *(const float4*)(B + (size_t)(k0 + skb + kk) * N + col0 + snb);
#pragma unroll
            for (int n = 0; n < 4; n++) {
                s16x4 w;
                w[0] = f2bf((&r4[0].x)[n]); w[1] = f2bf((&r4[1].x)[n]);
                w[2] = f2bf((&r4[2].x)[n]); w[3] = f2bf((&r4[3].x)[n]);
                *(s16x4*)&Bs[snb + n][skb] = w;
            }
        }
        __syncthreads();
#pragma unroll
        for (int kk = 0; kk < 64; kk += 32) {
            s16x8 a[4], b[2];
#pragma unroll
            for (int mi = 0; mi < 4; mi++) a[mi] = *(const s16x8*)&As[wm * 64 + mi * 16 + li][kk + g * 8];
#pragma unroll
            for (int ni = 0; ni < 2; ni++) b[ni] = *(const s16x8*)&Bs[wn * 32 + ni * 16 + li][kk + g * 8];
#pragma unroll
            for (int mi = 0; mi < 4; mi++)
#pragma unroll
                for (int ni = 0; ni < 2; ni++)
                    acc[mi][ni] = __builtin_amdgcn_mfma_f32_16x16x32_bf16(a[mi], b[ni], acc[mi][ni], 0, 0, 0);
        }
        __syncthreads();
    }
#pragma unroll
    for (int mi = 0; mi < 4; mi++)
#pragma unroll
        for (int ni = 0; ni < 2; ni++) {
            int gc = col0 + wn * 32 + ni * 16 + li;
#pragma unroll
            for (int r = 0; r < 4; r++) {
                int gr = wm * 64 + mi * 16 + g * 4 + r;
                if (gr < nrows) C[(size_t)gr * N + gc] = acc[mi][ni][r];
            }
        }
}

// ---------------- RoPE + build qf/kf/v as split planes ----------------
__global__ void prep_qkv_kernel(const float* __restrict__ q, const float* __restrict__ kva,
                                const float* __restrict__ kv, const int* __restrict__ positions,
                                short* __restrict__ qfh, short* __restrict__ qfl,
                                short* __restrict__ kfh, short* __restrict__ kfl,
                                short* __restrict__ vbh, short* __restrict__ vbl) {
    int t = blockIdx.x;
    __shared__ float cs[16], sn[16];
    if (threadIdx.x < 16) {
        float invf = powf(10000.f, -(float)(2 * threadIdx.x) / 32.f);
        float fr = (float)positions[t] * invf;
        cs[threadIdx.x] = cosf(fr);
        sn[threadIdx.x] = sinf(fr);
    }
    __syncthreads();
    for (int i = threadIdx.x; i < NH * QKD; i += blockDim.x) {
        int h = i / QKD, d = i % QKD;
        float val;
        if (d < 64) val = q[(size_t)t * 1536 + h * QKD + d];
        else {
            int r = d - 64, pr = r >> 1;
            float x1 = q[(size_t)t * 1536 + h * QKD + 64 + 2 * pr];
            float x2 = q[(size_t)t * 1536 + h * QKD + 64 + 2 * pr + 1];
            val = (r & 1) ? (x1 * sn[pr] + x2 * cs[pr]) : (x1 * cs[pr] - x2 * sn[pr]);
        }
        short hh = f2bf(val);
        qfh[(size_t)t * 1536 + i] = hh;
        qfl[(size_t)t * 1536 + i] = f2bf(val - bf2f(hh));
    }
    for (int i = threadIdx.x; i < NH * QKD; i += blockDim.x) {
        int h = i / QKD, d = i % QKD;
        float val;
        if (d < 64) val = kv[(size_t)t * 2048 + h * 128 + d];
        else {
            int r = d - 64, pr = r >> 1;
            float x1 = kva[(size_t)t * 288 + 256 + 2 * pr];
            float x2 = kva[(size_t)t * 288 + 256 + 2 * pr + 1];
            val = (r & 1) ? (x1 * sn[pr] + x2 * cs[pr]) : (x1 * cs[pr] - x2 * sn[pr]);
        }
        short hh = f2bf(val);
        kfh[(size_t)t * 1536 + i] = hh;
        kfl[(size_t)t * 1536 + i] = f2bf(val - bf2f(hh));
    }
    for (int i = threadIdx.x; i < NH * VD; i += blockDim.x) {
        int h = i / VD, d = i % VD;
        float val = kv[(size_t)t * 2048 + h * 128 + 64 + d];
        short hh = f2bf(val);
        vbh[(size_t)t * 1024 + i] = hh;
        vbl[(size_t)t * 1024 + i] = f2bf(val - bf2f(hh));
    }
}

// =====================================================================
// MFMA flash attention (verified; reads/writes bf16 planes)
// =====================================================================
__global__ __launch_bounds__(256) void attn_mfma_kernel(const short* __restrict__ qfh, const short* __restrict__ qfl,
                                                        const short* __restrict__ kfh, const short* __restrict__ kfl,
                                                        const short* __restrict__ vbh, const short* __restrict__ vbl,
                                                        short* __restrict__ obh, short* __restrict__ obl) {
    __shared__ short K_hi[64][104], K_lo[64][104];
    __shared__ short Vt_hi[64][72], Vt_lo[64][72];
    __shared__ short P_hi[4][16][72], P_lo[4][16][72];
    const int qt = blockIdx.x, h = blockIdx.y;
    const int tid = threadIdx.x, lane = tid & 63, w = tid >> 6;
    const int g = lane >> 4, li = lane & 15;

    s16x8 q_hi[3], q_lo[3];
    {
        const short* qb_h = qfh + (size_t)(qt * 64 + w * 16 + li) * 1536 + h * QKD;
        const short* qb_l = qfl + (size_t)(qt * 64 + w * 16 + li) * 1536 + h * QKD;
#pragma unroll
        for (int ks = 0; ks < 3; ks++) {
            q_hi[ks] = *(const s16x8*)(qb_h + ks * 32 + g * 8);
            q_lo[ks] = *(const s16x8*)(qb_l + ks * 32 + g * 8);
        }
    }

    f32x4 acc_o[4];
#pragma unroll
    for (int nc = 0; nc < 4; nc++)
#pragma unroll
        for (int r = 0; r < 4; r++) acc_o[nc][r] = 0.f;
    float m4[4] = {-1e30f, -1e30f, -1e30f, -1e30f};
    float l4[4] = {0.f, 0.f, 0.f, 0.f};
    const float scale = 0.102062072616f;

    for (int kt = 0; kt <= qt; kt++) {
#pragma unroll
        for (int it = 0; it < 3; it++) {
            int cid = it * 256 + tid;
            int key = cid / 12, c = cid % 12;
            *(s16x8*)&K_hi[key][c * 8] = *(const s16x8*)&kfh[(size_t)(kt * 64 + key) * 1536 + h * QKD + c * 8];
            *(s16x8*)&K_lo[key][c * 8] = *(const s16x8*)&kfl[(size_t)(kt * 64 + key) * 1536 + h * QKD + c * 8];
        }
#pragma unroll
        for (int it = 0; it < 2; it++) {
            int cid = it * 256 + tid;
            int key = cid >> 3, vc = cid & 7;
            s16x8 vh = *(const s16x8*)&vbh[(size_t)(kt * 64 + key) * 1024 + h * VD + vc * 8];
            s16x8 vl = *(const s16x8*)&vbl[(size_t)(kt * 64 + key) * 1024 + h * VD + vc * 8];
#pragma unroll
            for (int j = 0; j < 8; j++) {
                Vt_hi[vc * 8 + j][key] = vh[j];
                Vt_lo[vc * 8 + j][key] = vl[j];
            }
        }
        __syncthreads();

        f32x4 acc_s[4];
#pragma unroll
        for (int kc = 0; kc < 4; kc++)
#pragma unroll
            for (int r = 0; r < 4; r++) acc_s[kc][r] = 0.f;
#pragma unroll
        for (int ks = 0; ks < 3; ks++) {
#pragma unroll
            for (int kc = 0; kc < 4; kc++) {
                s16x8 kh = *(const s16x8*)&K_hi[kc * 16 + li][ks * 32 + g * 8];
                s16x8 kl = *(const s16x8*)&K_lo[kc * 16 + li][ks * 32 + g * 8];
                acc_s[kc] = __builtin_amdgcn_mfma_f32_16x16x32_bf16(q_hi[ks], kh, acc_s[kc], 0, 0, 0);
                acc_s[kc] = __builtin_amdgcn_mfma_f32_16x16x32_bf16(q_lo[ks], kh, acc_s[kc], 0, 0, 0);
                acc_s[kc] = __builtin_amdgcn_mfma_f32_16x16x32_bf16(q_hi[ks], kl, acc_s[kc], 0, 0, 0);
            }
        }
#pragma unroll
        for (int kc = 0; kc < 4; kc++)
#pragma unroll
            for (int r = 0; r < 4; r++) acc_s[kc][r] *= scale;
        if (kt == qt) {
#pragma unroll
            for (int kc = 0; kc < 4; kc++) {
                int key = kt * 64 + kc * 16 + li;
#pragma unroll
                for (int r = 0; r < 4; r++) {
                    int qr = qt * 64 + w * 16 + g * 4 + r;
                    if (key > qr) acc_s[kc][r] = -1e30f;
                }
            }
        }
        float tm[4];
#pragma unroll
        for (int r = 0; r < 4; r++)
            tm[r] = fmaxf(fmaxf(acc_s[0][r], acc_s[1][r]), fmaxf(acc_s[2][r], acc_s[3][r]));
#pragma unroll
        for (int off = 1; off < 16; off <<= 1)
#pragma unroll
            for (int r = 0; r < 4; r++) tm[r] = fmaxf(tm[r], __shfl_xor(tm[r], off));
        float alpha[4];
#pragma unroll
        for (int r = 0; r < 4; r++) {
            float mn = fmaxf(m4[r], tm[r]);
            alpha[r] = __expf(m4[r] - mn);
            m4[r] = mn;
        }
        float rs[4] = {0.f, 0.f, 0.f, 0.f};
#pragma unroll
        for (int kc = 0; kc < 4; kc++)
#pragma unroll
            for (int r = 0; r < 4; r++) {
                float p = __expf(acc_s[kc][r] - m4[r]);
                rs[r] += p;
                short hh = f2bf(p);
                P_hi[w][g * 4 + r][kc * 16 + li] = hh;
                P_lo[w][g * 4 + r][kc * 16 + li] = f2bf(p - bf2f(hh));
            }
#pragma unroll
        for (int off = 1; off < 16; off <<= 1)
#pragma unroll
            for (int r = 0; r < 4; r++) rs[r] += __shfl_xor(rs[r], off);
#pragma unroll
        for (int r = 0; r < 4; r++) l4[r] = l4[r] * alpha[r] + rs[r];
#pragma unroll
        for (int nc = 0; nc < 4; nc++)
#pragma unroll
            for (int r = 0; r < 4; r++) acc_o[nc][r] *= alpha[r];
#pragma unroll
        for (int ks = 0; ks < 2; ks++) {
            s16x8 ph = *(const s16x8*)&P_hi[w][li][ks * 32 + g * 8];
            s16x8 pl = *(const s16x8*)&P_lo[w][li][ks * 32 + g * 8];
#pragma unroll
            for (int nc = 0; nc < 4; nc++) {
                s16x8 vh = *(const s16x8*)&Vt_hi[nc * 16 + li][ks * 32 + g * 8];
                s16x8 vl = *(const s16x8*)&Vt_lo[nc * 16 + li][ks * 32 + g * 8];
                acc_o[nc] = __builtin_amdgcn_mfma_f32_16x16x32_bf16(ph, vh, acc_o[nc], 0, 0, 0);
                acc_o[nc] = __builtin_amdgcn_mfma_f32_16x16x32_bf16(pl, vh, acc_o[nc], 0, 0, 0);
                acc_o[nc] = __builtin_amdgcn_mfma_f32_16x16x32_bf16(ph, vl, acc_o[nc], 0, 0, 0);
            }
        }
        __syncthreads();
    }
    float inv[4];
#pragma unroll
    for (int r = 0; r < 4; r++) inv[r] = 1.f / l4[r];
#pragma unroll
    for (int nc = 0; nc < 4; nc++)
#pragma unroll
        for (int r = 0; r < 4; r++) {
            float o = acc_o[nc][r] * inv[r];
            size_t idx = (size_t)(qt * 64 + w * 16 + g * 4 + r) * 1024 + h * VD + nc * 16 + li;
            short hh = f2bf(o);
            obh[idx] = hh;
            obl[idx] = f2bf(o - bf2f(hh));
        }
}

// ---------------- routing ----------------
__global__ void routing_kernel(const float* __restrict__ h2, const float* __restrict__ gate_w,
                               const float* __restrict__ gate_bias, int* __restrict__ topidx,
                               float* __restrict__ topw) {
    int t = blockIdx.x;
    float acc[8] = {0.f, 0.f, 0.f, 0.f, 0.f, 0.f, 0.f, 0.f};
    for (int i = threadIdx.x; i < HDIM; i += blockDim.x) {
        float hv = h2[(size_t)t * HDIM + i];
        const float* g = gate_w + (size_t)i * 8;
#pragma unroll
        for (int e = 0; e < 8; e++) acc[e] = fmaf(hv, g[e], acc[e]);
    }
    __shared__ float logits[8];
    for (int e = 0; e < 8; e++) {
        float s = block_sum(acc[e]);
        if (threadIdx.x == 0) logits[e] = s;
    }
    __syncthreads();
    if (threadIdx.x == 0) {
        float sig[8], sc[8];
        for (int e = 0; e < 8; e++) {
            sig[e] = 1.f / (1.f + expf(-logits[e]));
            sc[e] = sig[e] + gate_bias[e];
        }
        int i0 = 0;
        for (int e = 1; e < 8; e++) if (sc[e] > sc[i0]) i0 = e;
        int i1 = -1;
        for (int e = 0; e < 8; e++) if (e != i0 && (i1 < 0 || sc[e] > sc[i1])) i1 = e;
        float w0 = sig[i0], w1 = sig[i1], s = w0 + w1 + 1e-20f;
        topidx[t * 2 + 0] = i0; topidx[t * 2 + 1] = i1;
        topw[t * 2 + 0] = w0 / s; topw[t * 2 + 1] = w1 / s;
    }
}

// ---------------- counting sort + tile map ----------------
__global__ void sort_kernel(const int* __restrict__ topidx, int* __restrict__ sorted_t,
                            int* __restrict__ slotpos, int4* __restrict__ tilemap) {
    __shared__ int counts[8], offs[9];
    int wid = threadIdx.x >> 6, lane = threadIdx.x & 63;
    int cnt = 0;
    for (int base = 0; base < 2 * T_; base += 64) {
        int e = topidx[base + lane];
        unsigned long long m = __ballot(e == wid);
        cnt += __popcll(m);
    }
    if (lane == 0) counts[wid] = cnt;
    __syncthreads();
    if (threadIdx.x == 0) {
        offs[0] = 0;
        for (int e = 0; e < 8; e++) offs[e + 1] = offs[e] + counts[e];
    }
    __syncthreads();
    int pos = offs[wid];
    for (int base = 0; base < 2 * T_; base += 64) {
        int sl = base + lane;
        int e = topidx[sl];
        bool match = (e == wid);
        unsigned long long m = __ballot(match);
        if (match) {
            int before = __popcll(m & ((1ull << lane) - 1ull));
            int pp = pos + before;
            sorted_t[pp] = sl >> 1;
            slotpos[sl] = pp;
        }
        pos += __popcll(m);
    }
    __syncthreads();
    if (threadIdx.x == 0) {
        int nt = 0;
        for (int e = 0; e < 8; e++) {
            int c = counts[e], o = offs[e];
            for (int r = 0; r < c; r += 128) {
                tilemap[nt] = make_int4(e, o + r, min(128, c - r), 0);
                nt++;
            }
        }
        for (int i = nt; i < MAXTILES; i++) tilemap[i] = make_int4(0, 0, 0, 0);
    }
}

// ---------------- gather h2 rows (f32, for MoE) ----------------
__global__ void gather_kernel(const float* __restrict__ h2, const int* __restrict__ sorted_t,
                              float* __restrict__ gout) {
    int pp = blockIdx.x;
    int t = sorted_t[pp];
    const float4* src = (const float4*)(h2 + (size_t)t * HDIM);
    float4* dst = (float4*)(gout + (size_t)pp * HDIM);
    for (int i = threadIdx.x; i < HDIM / 4; i += blockDim.x) dst[i] = src[i];
}

// ---------------- elementwise ----------------
__global__ void silu_mul_kernel(float* __restrict__ g, const float* __restrict__ u, int n) {
    int stride = gridDim.x * blockDim.x;
    for (int i = blockIdx.x * blockDim.x + threadIdx.x; i < n; i += stride) {
        float x = g[i];
        g[i] = (x / (1.f + expf(-x))) * u[i];
    }
}

__global__ void silu_mul_bf16_kernel(const float* __restrict__ g, const float* __restrict__ u,
                                     short* __restrict__ outh, int n) {
    int stride = gridDim.x * blockDim.x;
    for (int i = blockIdx.x * blockDim.x + threadIdx.x; i < n; i += stride) {
        float x = g[i];
        outh[i] = f2bf((x / (1.f + expf(-x))) * u[i]);
    }
}

__global__ void add_inplace_kernel(float* __restrict__ x, const float* __restrict__ y, int n) {
    int stride = gridDim.x * blockDim.x;
    for (int i = blockIdx.x * blockDim.x + threadIdx.x; i < n; i += stride) x[i] += y[i];
}

// ---------------- final combine -> f32 out ----------------
__global__ void final_kernel(const float* __restrict__ resid, const float* __restrict__ sho,
                             const float* __restrict__ md, const int* __restrict__ slotpos,
                             const float* __restrict__ topw, float* __restrict__ out) {
    int t = blockIdx.x;
    int p0 = slotpos[t * 2 + 0], p1 = slotpos[t * 2 + 1];
    float w0 = topw[t * 2 + 0] * 2.5f, w1 = topw[t * 2 + 1] * 2.5f;
    for (int c = threadIdx.x; c < HDIM; c += blockDim.x) {
        float v = resid[(size_t)t * HDIM + c] + sho[(size_t)t * HDIM + c]
                + w0 * md[(size_t)p0 * HDIM + c] + w1 * md[(size_t)p1 * HDIM + c];
        out[(size_t)t * HDIM + c] = v;
    }
}

// ---------------- launcher ----------------
extern "C" void kernel_launch(void* const* d_in, const int* in_sizes, int n_in,
                              void* d_out, int out_size, void* d_ws, size_t ws_size,
                              hipStream_t stream) {
    (void)in_sizes; (void)n_in; (void)out_size; (void)ws_size;
    const int*   input_ids = (const int*)d_in[0];
    const int*   positions = (const int*)d_in[1];
    const float* prev      = (const float*)d_in[2];
    const float* embed     = (const float*)d_in[3];
    const float* enorm_w   = (const float*)d_in[4];
    const float* hnorm_w   = (const float*)d_in[5];
    const float* eh_proj_w = (const float*)d_in[6];
    const float* in_ln_w   = (const float*)d_in[7];
    const float* post_ln_w = (const float*)d_in[8];
    const float* q_a_w     = (const float*)d_in[9];
    const float* q_a_ln_w  = (const float*)d_in[10];
    const float* q_b_w     = (const float*)d_in[11];
    const float* kv_a_w    = (const float*)d_in[12];
    const float* kv_a_ln_w = (const float*)d_in[13];
    const float* kv_b_w    = (const float*)d_in[14];
    const float* o_w       = (const float*)d_in[15];
    const float* gate_w    = (const float*)d_in[16];
    const float* gate_bias = (const float*)d_in[17];
    const float* exp_g     = (const float*)d_in[18];
    const float* exp_u     = (const float*)d_in[19];
    const float* exp_d     = (const float*)d_in[20];
    const float* sh_g      = (const float*)d_in[21];
    const float* sh_u      = (const float*)d_in[22];
    const float* sh_d      = (const float*)d_in[23];
    float* out = (float*)d_out;

    float* ws = (float*)d_ws;
    short* catH  = (short*)(ws + OF_CATH);
    short* catL  = (short*)(ws + OF_CATL);
    float* gath  = ws + OF_GATH;
    float* x0    = ws + OF_X0;
    float* h2    = ws + OF_H2;
    short* hH    = (short*)(ws + OF_HH);
    short* hL    = (short*)(ws + OF_HL);
    float* sho   = ws + OF_SHO;
    float* qraw  = ws + OF_QRAW;
    float* qbuf  = ws + OF_QBUF;
    float* kva   = ws + OF_KVA;
    float* kvbuf = ws + OF_KVBUF;
    float* md    = ws + OF_MD;
    short* qaH   = (short*)(ws + OF_QAH);
    short* qaL   = (short*)(ws + OF_QAL);
    short* kvcnH = (short*)(ws + OF_KVCNH);
    short* kvcnL = (short*)(ws + OF_KVCNL);
    short* qfH   = (short*)(ws + OF_QFH);
    short* qfL   = (short*)(ws + OF_QFL);
    short* kfH   = (short*)(ws + OF_KFH);
    short* kfL   = (short*)(ws + OF_KFL);
    short* vbH   = (short*)(ws + OF_VBH);
    short* vbL   = (short*)(ws + OF_VBL);
    float* mg    = ws + OF_MG;
    float* mu    = ws + OF_MU;
    short* obH   = (short*)(ws + OF_OBH);
    short* obL   = (short*)(ws + OF_OBL);
    float* att   = ws + OF_ATT;
    float* sg    = ws + OF_SG;
    float* su    = ws + OF_SU;
    short* h2bf  = (short*)(ws + OF_H2BF);
    short* sgact = (short*)(ws + OF_SGACT);
    int*   ri       = (int*)(ws + OF_ROUT);
    int*   topidx   = ri;
    int*   sorted_t = ri + 2048;
    int*   slotpos  = ri + 4096;
    int4*  tilemap  = (int4*)(ri + 6144);
    float* topw     = (float*)(ri + 6144 + 4 * MAXTILES);
    short* ehTH  = (short*)(ws + OF_EHTH);
    short* ehTL  = (short*)(ws + OF_EHTL);
    short* qaTH  = (short*)(ws + OF_QATH);
    short* qaTL  = (short*)(ws + OF_QATL);
    short* qbTH  = (short*)(ws + OF_QBTH);
    short* qbTL  = (short*)(ws + OF_QBTL);
    short* kvaTH = (short*)(ws + OF_KVATH);
    short* kvaTL = (short*)(ws + OF_KVATL);
    short* kvbTH = (short*)(ws + OF_KVBTH);
    short* kvbTL = (short*)(ws + OF_KVBTL);
    short* owTH  = (short*)(ws + OF_OWTH);
    short* owTL  = (short*)(ws + OF_OWTL);
    short* shgT  = (short*)(ws + OF_SHGT);
    short* shuT  = (short*)(ws + OF_SHUT);
    short* shdT  = (short*)(ws + OF_SHDT);

    dim3 blk(256);

    // 0. weight transpose+split (round-6 grids)
    transpose_split_kernel<<<dim3(64, 32), blk, 0, stream>>>(eh_proj_w, ehTH, ehTL, 4096, 2048, 1);
    transpose_split_kernel<<<dim3(32, 8), blk, 0, stream>>>(q_a_w, qaTH, qaTL, 2048, 512, 1);
    transpose_split_kernel<<<dim3(8, 24), blk, 0, stream>>>(q_b_w, qbTH, qbTL, 512, 1536, 1);
    transpose_split_kernel<<<dim3(32, 6), blk, 0, stream>>>(kv_a_w, kvaTH, kvaTL, 2048, 288, 1);
    transpose_split_kernel<<<dim3(4, 32), blk, 0, stream>>>(kv_b_w, kvbTH, kvbTL, 256, 2048, 1);
    transpose_split_kernel<<<dim3(16, 32), blk, 0, stream>>>(o_w, owTH, owTL, 1024, 2048, 1);
    transpose_split_kernel<<<dim3(32, 16), blk, 0, stream>>>(sh_g, shgT, nullptr, 2048, 1024, 0);
    transpose_split_kernel<<<dim3(32, 16), blk, 0, stream>>>(sh_u, shuT, nullptr, 2048, 1024, 0);
    transpose_split_kernel<<<dim3(16, 32), blk, 0, stream>>>(sh_d, shdT, nullptr, 1024, 2048, 0);

    // 1. embed + rmsnorm + concat
    embed_cat_kernel<<<T_, blk, 0, stream>>>(input_ids, embed, enorm_w, prev, hnorm_w, catH, catL);
    // 2. x0 = cat @ eh_proj  (BN=128 grids from here on)
    gemm_planes<true><<<dim3(16, 8), blk, 0, stream>>>(catH, catL, ehTH, ehTL, x0, T_, 2048, 4096);
    // 3. h = rmsnorm(x0)
    rmsnorm_kernel<<<T_, blk, 0, stream>>>(x0, 2048, 2048, in_ln_w, nullptr, hH, hL, 2048);
    // 4. q_a
    gemm_planes<true><<<dim3(4, 8), blk, 0, stream>>>(hH, hL, qaTH, qaTL, qraw, T_, 512, 2048);
    rmsnorm_kernel<<<T_, blk, 0, stream>>>(qraw, 512, 512, q_a_ln_w, nullptr, qaH, qaL, 512);
    // 5. q = qa @ q_b
    gemm_planes<true><<<dim3(12, 8), blk, 0, stream>>>(qaH, qaL, qbTH, qbTL, qbuf, T_, 1536, 512);
    // 6. kva = h @ kv_a (planes padded to 384 rows)
    gemm_planes<true><<<dim3(3, 8), blk, 0, stream>>>(hH, hL, kvaTH, kvaTL, kva, T_, 288, 2048);
    // 7. kvcn
    rmsnorm_kernel<<<T_, blk, 0, stream>>>(kva, 288, 256, kv_a_ln_w, nullptr, kvcnH, kvcnL, 256);
    // 8. kv = kvcn @ kv_b
    gemm_planes<true><<<dim3(16, 8), blk, 0, stream>>>(kvcnH, kvcnL, kvbTH, kvbTL, kvbuf, T_, 2048, 256);
    // 9. rope + planes
    prep_qkv_kernel<<<T_, blk, 0, stream>>>(qbuf, kva, kvbuf, positions, qfH, qfL, kfH, kfL, vbH, vbL);
    // 10. flash attention
    attn_mfma_kernel<<<dim3(T_ / 64, NH), blk, 0, stream>>>(qfH, qfL, kfH, kfL, vbH, vbL, obH, obL);
    // 11. attn_out = ob @ o_w
    gemm_planes<true><<<dim3(16, 8), blk, 0, stream>>>(obH, obL, owTH, owTL, att, T_, 2048, 1024);
    // 12. resid += attn_out
    add_inplace_kernel<<<2048, blk, 0, stream>>>(x0, att, T_ * 2048);
    // 13. h2 = rmsnorm(resid): f32 (routing/gather) + hi plane (shared GEMMs)
    rmsnorm_kernel<<<T_, blk, 0, stream>>>(x0, 2048, 2048, post_ln_w, h2, h2bf, nullptr, 2048);
    // 14. routing
    routing_kernel<<<T_, blk, 0, stream>>>(h2, gate_w, gate_bias, topidx, topw);
    // 15. sort
    sort_kernel<<<1, 512, 0, stream>>>(topidx, sorted_t, slotpos, tilemap);
    // 16. gather (f32)
    gather_kernel<<<2 * T_, blk, 0, stream>>>(h2, sorted_t, gath);
    // 17. MoE gate/up (round-6 moe_gemm_bf16, BN=64)
    moe_gemm_bf16<<<dim3(16, MAXTILES), blk, 0, stream>>>(gath, exp_g, mg, tilemap, 2048, 1024);
    moe_gemm_bf16<<<dim3(16, MAXTILES), blk, 0, stream>>>(gath, exp_u, mu, tilemap, 2048, 1024);
    // 18. silu
    silu_mul_kernel<<<2048, blk, 0, stream>>>(mg, mu, 2048 * 1024);
    // 19. MoE down
    moe_gemm_bf16<<<dim3(32, MAXTILES), blk, 0, stream>>>(mg, exp_d, md, tilemap, 1024, 2048);
    // 20. shared MLP
    gemm_planes<false><<<dim3(8, 8), blk, 0, stream>>>(h2bf, h2bf, shgT, shgT, sg, T_, 1024, 2048);
    gemm_planes<false><<<dim3(8, 8), blk, 0, stream>>>(h2bf, h2bf, shuT, shuT, su, T_, 1024, 2048);
    silu_mul_bf16_kernel<<<1024, blk, 0, stream>>>(sg, su, sgact, T_ * 1024);
    gemm_planes<false><<<dim3(16, 8), blk, 0, stream>>>(sgact, sgact, shdT, shdT, sho, T_, 2048, 1024);
    // 21. final combine
    final_kernel<<<T_, blk, 0, stream>>>(x0, sho, md, slotpos, topw, out);
}

// Round 9
// 746.255 us; speedup vs baseline: 1.2884x; 1.2884x over previous
//
#include <hip/hip_runtime.h>
#include <hip/hip_bf16.h>
#include <math.h>

constexpr int T_ = 1024;
constexpr int HDIM = 2048;
constexpr int NH = 16;
constexpr int QKD = 96;
constexpr int VD = 64;
constexpr int MAXTILES = 24;
constexpr float EPSF = 1e-6f;

using f32x4 = __attribute__((ext_vector_type(4))) float;
using s16x8 = __attribute__((ext_vector_type(8))) short;
using s16x4 = __attribute__((ext_vector_type(4))) short;

// ---------------- workspace layout (round-6 verified, 165 MB cap; float offsets) ----------------
constexpr size_t OF_CATH  = 0;                 // bf16 T*4096
constexpr size_t OF_CATL  = 2097152;
constexpr size_t OF_GACT  = 0;                 // bf16 2048*2048 (alias cat planes; disjoint lifetime)
constexpr size_t OF_X0    = 4194304;           // f32 T*2048
constexpr size_t OF_MACT  = 6291456;           // bf16 2048*1024 (old h2 slot, now free)
constexpr size_t OF_HH    = 8388608;           // bf16 T*2048
constexpr size_t OF_HL    = 9437184;
constexpr size_t OF_SHO   = 8388608;           // f32 T*2048 (alias h planes)
constexpr size_t OF_QRAW  = 10485760;          // f32 T*512
constexpr size_t OF_QBUF  = 11010048;          // f32 T*1536
constexpr size_t OF_KVA   = 12582912;          // f32 T*288
constexpr size_t OF_KVBUF = 12877824;          // f32 T*2048
constexpr size_t OF_MD    = 10485760;          // f32 2048*2048 (alias qraw..kvbuf)
constexpr size_t OF_QAH   = 14974976;          // bf16 T*512
constexpr size_t OF_QAL   = 15237120;
constexpr size_t OF_KVCNH = 15499264;          // bf16 T*256
constexpr size_t OF_KVCNL = 15630336;
constexpr size_t OF_QFH   = 15761408;          // bf16 T*1536
constexpr size_t OF_QFL   = 16547840;
constexpr size_t OF_KFH   = 17334272;
constexpr size_t OF_KFL   = 18120704;
constexpr size_t OF_VBH   = 18907136;          // bf16 T*1024
constexpr size_t OF_VBL   = 19431424;
constexpr size_t OF_OBH   = 19955712;          // bf16 T*1024
constexpr size_t OF_OBL   = 20480000;
constexpr size_t OF_ATT   = 21004288;          // f32 T*2048
constexpr size_t OF_SG    = 21004288;          // f32 T*1024 (alias att; att dead after fuse)
constexpr size_t OF_SU    = 22052864;          // f32 T*1024
constexpr size_t OF_H2BF  = 23101440;          // bf16 T*2048
constexpr size_t OF_SGACT = 24150016;          // bf16 T*1024
constexpr size_t OF_ROUT  = 24674304;          // ints
// weight planes (bf16)
constexpr size_t OF_EHTH  = 24682752;          // [2048][4096]
constexpr size_t OF_EHTL  = 28877056;
constexpr size_t OF_QATH  = 33071360;          // [512][2048]
constexpr size_t OF_QATL  = 33595648;
constexpr size_t OF_QBTH  = 34119936;          // [1536][512]
constexpr size_t OF_QBTL  = 34513152;
constexpr size_t OF_KVATH = 34906368;          // [320][2048] (288 used; grid writes rows<320 only)
constexpr size_t OF_KVATL = 35234048;
constexpr size_t OF_KVBTH = 35561728;          // [2048][256]
constexpr size_t OF_KVBTL = 35823872;
constexpr size_t OF_OWTH  = 36086016;          // [2048][1024]
constexpr size_t OF_OWTL  = 37134592;
constexpr size_t OF_SHGT  = 38183168;          // [1024][2048]
constexpr size_t OF_SHUT  = 39231744;
constexpr size_t OF_SHDT  = 40280320;          // [2048][1024]  (ends 41328896 floats = 165 MB)

// ---------------- helpers ----------------
__device__ __forceinline__ short f2bf(float f) {
    union { float f; unsigned u; } x; x.f = f;
    unsigned r = x.u + 0x7fffu + ((x.u >> 16) & 1u);
    return (short)(r >> 16);
}
__device__ __forceinline__ float bf2f(short h) {
    union { unsigned u; float f; } x; x.u = ((unsigned)(unsigned short)h) << 16; return x.f;
}
// LDS swizzle (plane GEMM): row stride 64 shorts; chunk ^= row&7
__device__ __forceinline__ int swz(int r, int k) {
    return (r << 6) + ((((k >> 3) ^ (r & 7)) << 3) | (k & 7));
}

__device__ __forceinline__ float block_sum(float v) {
    __shared__ float sbuf[9];
    int lane = threadIdx.x & 63;
    int wid  = threadIdx.x >> 6;
#pragma unroll
    for (int off = 32; off > 0; off >>= 1) v += __shfl_down(v, off);
    __syncthreads();
    if (lane == 0) sbuf[wid] = v;
    __syncthreads();
    if (threadIdx.x == 0) {
        float s = 0.f;
        int nw = blockDim.x >> 6;
        for (int i = 0; i < nw; i++) s += sbuf[i];
        sbuf[8] = s;
    }
    __syncthreads();
    return sbuf[8];
}

// ---------------- weight transpose + split ----------------
__global__ void transpose_split_kernel(const float* __restrict__ W, short* __restrict__ Whi,
                                       short* __restrict__ Wlo, int K, int N, int split) {
    __shared__ float tile[64][65];
    int k0 = blockIdx.x * 64, n0 = blockIdx.y * 64;
    int tn = threadIdx.x & 63;
    int tk4 = threadIdx.x >> 6;
#pragma unroll 4
    for (int i = 0; i < 16; i++) {
        int kk = tk4 * 16 + i;
        int gn = n0 + tn;
        tile[kk][tn] = (gn < N) ? W[(size_t)(k0 + kk) * N + gn] : 0.f;
    }
    __syncthreads();
    int on = threadIdx.x >> 2;
    int oc = threadIdx.x & 3;
#pragma unroll 4
    for (int i = 0; i < 16; i++) {
        int kk = oc * 16 + i;
        float v = tile[kk][on];
        short hh = f2bf(v);
        size_t o = (size_t)(n0 + on) * K + k0 + kk;
        Whi[o] = hh;
        if (split) Wlo[o] = f2bf(v - bf2f(hh));
    }
}

// ---------------- embedding + rmsnorm + concat -> split planes ----------------
__global__ void embed_cat_kernel(const int* __restrict__ ids, const float* __restrict__ embed,
                                 const float* __restrict__ enorm, const float* __restrict__ prev,
                                 const float* __restrict__ hnorm, short* __restrict__ ch,
                                 short* __restrict__ cl) {
    int t = blockIdx.x;
    const float* e = embed + (size_t)ids[t] * HDIM;
    float ss = 0.f;
    for (int i = threadIdx.x; i < HDIM; i += blockDim.x) { float v = e[i]; ss += v * v; }
    float r = rsqrtf(block_sum(ss) / HDIM + EPSF);
    for (int i = threadIdx.x; i < HDIM; i += blockDim.x) {
        float v = e[i] * r * enorm[i];
        short hh = f2bf(v);
        ch[(size_t)t * 4096 + i] = hh;
        cl[(size_t)t * 4096 + i] = f2bf(v - bf2f(hh));
    }
    const float* p = prev + (size_t)t * HDIM;
    ss = 0.f;
    for (int i = threadIdx.x; i < HDIM; i += blockDim.x) { float v = p[i]; ss += v * v; }
    r = rsqrtf(block_sum(ss) / HDIM + EPSF);
    for (int i = threadIdx.x; i < HDIM; i += blockDim.x) {
        float v = p[i] * r * hnorm[i];
        short hh = f2bf(v);
        ch[(size_t)t * 4096 + 2048 + i] = hh;
        cl[(size_t)t * 4096 + 2048 + i] = f2bf(v - bf2f(hh));
    }
}

// ---------------- rmsnorm (f32 / hi / lo outputs) ----------------
__global__ void rmsnorm_kernel(const float* __restrict__ in, int in_stride, int width,
                               const float* __restrict__ w, float* __restrict__ outf,
                               short* __restrict__ outh, short* __restrict__ outl, int out_stride) {
    int t = blockIdx.x;
    const float* x = in + (size_t)t * in_stride;
    float ss = 0.f;
    for (int i = threadIdx.x; i < width; i += blockDim.x) { float v = x[i]; ss += v * v; }
    float r = rsqrtf(block_sum(ss) / width + EPSF);
    size_t ob = (size_t)t * out_stride;
    for (int i = threadIdx.x; i < width; i += blockDim.x) {
        float v = x[i] * r * w[i];
        if (outf) outf[ob + i] = v;
        if (outh) {
            short hh = f2bf(v);
            outh[ob + i] = hh;
            if (outl) outl[ob + i] = f2bf(v - bf2f(hh));
        }
    }
}

// =====================================================================
// Plane GEMM (round-6 verified): BM=128 BN=64 BK=64, swizzled LDS.
// =====================================================================
template<bool SPLIT>
__global__ __launch_bounds__(256) void gemm_planes(const short* __restrict__ Ahi, const short* __restrict__ Alo,
                                                   const short* __restrict__ Bhi, const short* __restrict__ Blo,
                                                   float* __restrict__ C, int M, int N, int K) {
    __shared__ short As[SPLIT ? 2 : 1][128 * 64];
    __shared__ short Bs[SPLIT ? 2 : 1][64 * 64];
    const int tid = threadIdx.x;
    const int lane = tid & 63, wid = tid >> 6;
    const int g = lane >> 4, li = lane & 15;
    const int wm = wid >> 1, wn = wid & 1;
    const int row0 = blockIdx.y * 128, col0 = blockIdx.x * 64;

    f32x4 acc[4][2];
#pragma unroll
    for (int mi = 0; mi < 4; mi++)
#pragma unroll
        for (int ni = 0; ni < 2; ni++)
#pragma unroll
            for (int r = 0; r < 4; r++) acc[mi][ni][r] = 0.f;

    for (int k0 = 0; k0 < K; k0 += 64) {
#pragma unroll
        for (int i = 0; i < 4; i++) {
            int cid = i * 256 + tid;
            int r = cid >> 3, c = cid & 7;
            *(s16x8*)&As[0][swz(r, c * 8)] = *(const s16x8*)&Ahi[(size_t)(row0 + r) * K + k0 + c * 8];
            if constexpr (SPLIT)
                *(s16x8*)&As[1][swz(r, c * 8)] = *(const s16x8*)&Alo[(size_t)(row0 + r) * K + k0 + c * 8];
        }
#pragma unroll
        for (int i = 0; i < 2; i++) {
            int cid = i * 256 + tid;
            int r = cid >> 3, c = cid & 7;
            *(s16x8*)&Bs[0][swz(r, c * 8)] = *(const s16x8*)&Bhi[(size_t)(col0 + r) * K + k0 + c * 8];
            if constexpr (SPLIT)
                *(s16x8*)&Bs[1][swz(r, c * 8)] = *(const s16x8*)&Blo[(size_t)(col0 + r) * K + k0 + c * 8];
        }
        __syncthreads();
#pragma unroll
        for (int kk = 0; kk < 64; kk += 32) {
            s16x8 ah[4], bh[2];
#pragma unroll
            for (int mi = 0; mi < 4; mi++) ah[mi] = *(const s16x8*)&As[0][swz(wm * 64 + mi * 16 + li, kk + g * 8)];
#pragma unroll
            for (int ni = 0; ni < 2; ni++) bh[ni] = *(const s16x8*)&Bs[0][swz(wn * 32 + ni * 16 + li, kk + g * 8)];
            if constexpr (SPLIT) {
                s16x8 al[4], bl[2];
#pragma unroll
                for (int mi = 0; mi < 4; mi++) al[mi] = *(const s16x8*)&As[1][swz(wm * 64 + mi * 16 + li, kk + g * 8)];
#pragma unroll
                for (int ni = 0; ni < 2; ni++) bl[ni] = *(const s16x8*)&Bs[1][swz(wn * 32 + ni * 16 + li, kk + g * 8)];
#pragma unroll
                for (int mi = 0; mi < 4; mi++)
#pragma unroll
                    for (int ni = 0; ni < 2; ni++) {
                        acc[mi][ni] = __builtin_amdgcn_mfma_f32_16x16x32_bf16(ah[mi], bh[ni], acc[mi][ni], 0, 0, 0);
                        acc[mi][ni] = __builtin_amdgcn_mfma_f32_16x16x32_bf16(al[mi], bh[ni], acc[mi][ni], 0, 0, 0);
                        acc[mi][ni] = __builtin_amdgcn_mfma_f32_16x16x32_bf16(ah[mi], bl[ni], acc[mi][ni], 0, 0, 0);
                    }
            } else {
#pragma unroll
                for (int mi = 0; mi < 4; mi++)
#pragma unroll
                    for (int ni = 0; ni < 2; ni++)
                        acc[mi][ni] = __builtin_amdgcn_mfma_f32_16x16x32_bf16(ah[mi], bh[ni], acc[mi][ni], 0, 0, 0);
            }
        }
        __syncthreads();
    }
#pragma unroll
    for (int mi = 0; mi < 4; mi++)
#pragma unroll
        for (int ni = 0; ni < 2; ni++) {
            int gc = col0 + wn * 32 + ni * 16 + li;
            if (gc < N) {
#pragma unroll
                for (int r = 0; r < 4; r++) {
                    int gr = row0 + wm * 64 + mi * 16 + g * 4 + r;
                    C[(size_t)gr * N + gc] = acc[mi][ni][r];
                }
            }
        }
}

// =====================================================================
// MoE gate+up fused GEMM + silu epilogue: A bf16 [slots][2048];
// Wg/Wu f32 [e][2048][1024]; out mact bf16. BM=128 BN=64 BK=64.
// =====================================================================
__global__ __launch_bounds__(256) void moe_gateup(const short* __restrict__ Abase, const float* __restrict__ Wg,
                                                  const float* __restrict__ Wu, short* __restrict__ Cact,
                                                  const int4* __restrict__ tilemap, int K, int N) {
    int4 tm = tilemap[blockIdx.y];
    int nrows = tm.z;
    if (nrows == 0) return;
    const short* A = Abase + (size_t)tm.y * K;
    const float* Bg = Wg + (size_t)tm.x * K * N;
    const float* Bu = Wu + (size_t)tm.x * K * N;

    alignas(16) __shared__ short As[128][72];
    alignas(16) __shared__ short Bgs[64][72];
    alignas(16) __shared__ short Bus[64][72];
    const int tid = threadIdx.x;
    const int lane = tid & 63, wid = tid >> 6;
    const int g = lane >> 4, li = lane & 15;
    const int wm = wid >> 1, wn = wid & 1;
    const int col0 = blockIdx.x * 64;

    f32x4 accg[4][2], accu[4][2];
#pragma unroll
    for (int mi = 0; mi < 4; mi++)
#pragma unroll
        for (int ni = 0; ni < 2; ni++)
#pragma unroll
            for (int r = 0; r < 4; r++) { accg[mi][ni][r] = 0.f; accu[mi][ni][r] = 0.f; }

    const int skb = (tid >> 4) << 2, snb = (tid & 15) << 2;

    for (int k0 = 0; k0 < K; k0 += 64) {
        // stage A (bf16 direct): 1024 chunks of 8, 4/thread
#pragma unroll
        for (int i = 0; i < 4; i++) {
            int cid = i * 256 + tid;
            int r = cid >> 3, c = cid & 7;
            s16x8 v;
            if (r < nrows) v = *(const s16x8*)&A[(size_t)r * K + k0 + c * 8];
            else {
#pragma unroll
                for (int j = 0; j < 8; j++) v[j] = 0;
            }
            *(s16x8*)&As[r][c * 8] = v;
        }
        // stage both B tiles (f32 -> bf16)
        {
            float4 rg[4], ru[4];
#pragma unroll
            for (int kk = 0; kk < 4; kk++) {
                rg[kk] = *(const float4*)(Bg + (size_t)(k0 + skb + kk) * N + col0 + snb);
                ru[kk] = *(const float4*)(Bu + (size_t)(k0 + skb + kk) * N + col0 + snb);
            }
#pragma unroll
            for (int n = 0; n < 4; n++) {
                s16x4 wg4, wu4;
                wg4[0] = f2bf((&rg[0].x)[n]); wg4[1] = f2bf((&rg[1].x)[n]);
                wg4[2] = f2bf((&rg[2].x)[n]); wg4[3] = f2bf((&rg[3].x)[n]);
                wu4[0] = f2bf((&ru[0].x)[n]); wu4[1] = f2bf((&ru[1].x)[n]);
                wu4[2] = f2bf((&ru[2].x)[n]); wu4[3] = f2bf((&ru[3].x)[n]);
                *(s16x4*)&Bgs[snb + n][skb] = wg4;
                *(s16x4*)&Bus[snb + n][skb] = wu4;
            }
        }
        __syncthreads();
#pragma unroll
        for (int kk = 0; kk < 64; kk += 32) {
            s16x8 a[4], bg2[2], bu2[2];
#pragma unroll
            for (int mi = 0; mi < 4; mi++) a[mi] = *(const s16x8*)&As[wm * 64 + mi * 16 + li][kk + g * 8];
#pragma unroll
            for (int ni = 0; ni < 2; ni++) {
                bg2[ni] = *(const s16x8*)&Bgs[wn * 32 + ni * 16 + li][kk + g * 8];
                bu2[ni] = *(const s16x8*)&Bus[wn * 32 + ni * 16 + li][kk + g * 8];
            }
#pragma unroll
            for (int mi = 0; mi < 4; mi++)
#pragma unroll
                for (int ni = 0; ni < 2; ni++) {
                    accg[mi][ni] = __builtin_amdgcn_mfma_f32_16x16x32_bf16(a[mi], bg2[ni], accg[mi][ni], 0, 0, 0);
                    accu[mi][ni] = __builtin_amdgcn_mfma_f32_16x16x32_bf16(a[mi], bu2[ni], accu[mi][ni], 0, 0, 0);
                }
        }
        __syncthreads();
    }
#pragma unroll
    for (int mi = 0; mi < 4; mi++)
#pragma unroll
        for (int ni = 0; ni < 2; ni++) {
            int gc = col0 + wn * 32 + ni * 16 + li;
#pragma unroll
            for (int r = 0; r < 4; r++) {
                int gr = wm * 64 + mi * 16 + g * 4 + r;
                if (gr < nrows) {
                    float x = accg[mi][ni][r], u = accu[mi][ni][r];
                    Cact[(size_t)(tm.y + gr) * N + gc] = f2bf((x / (1.f + expf(-x))) * u);
                }
            }
        }
}

// =====================================================================
// MoE down GEMM: A bf16 (mact) [slots][1024]; Wd f32 [e][1024][2048]; out md f32.
// =====================================================================
__global__ __launch_bounds__(256) void moe_down(const short* __restrict__ Abase, const float* __restrict__ Wall,
                                                float* __restrict__ Cbase, const int4* __restrict__ tilemap,
                                                int K, int N) {
    int4 tm = tilemap[blockIdx.y];
    int nrows = tm.z;
    if (nrows == 0) return;
    const short* A = Abase + (size_t)tm.y * K;
    float* C = Cbase + (size_t)tm.y * N;
    const float* B = Wall + (size_t)tm.x * K * N;

    alignas(16) __shared__ short As[128][72];
    alignas(16) __shared__ short Bs[64][72];
    const int tid = threadIdx.x;
    const int lane = tid & 63, wid = tid >> 6;
    const int g = lane >> 4, li = lane & 15;
    const int wm = wid >> 1, wn = wid & 1;
    const int col0 = blockIdx.x * 64;

    f32x4 acc[4][2];
#pragma unroll
    for (int mi = 0; mi < 4; mi++)
#pragma unroll
        for (int ni = 0; ni < 2; ni++)
#pragma unroll
            for (int r = 0; r < 4; r++) acc[mi][ni][r] = 0.f;

    const int skb = (tid >> 4) << 2, snb = (tid & 15) << 2;

    for (int k0 = 0; k0 < K; k0 += 64) {
#pragma unroll
        for (int i = 0; i < 4; i++) {
            int cid = i * 256 + tid;
            int r = cid >> 3, c = cid & 7;
            s16x8 v;
            if (r < nrows) v = *(const s16x8*)&A[(size_t)r * K + k0 + c * 8];
            else {
#pragma unroll
                for (int j = 0; j < 8; j++) v[j] = 0;
            }
            *(s16x8*)&As[r][c * 8] = v;
        }
        {
            float4 r4[4];
#pragma unroll
            for (int kk = 0; kk < 4; kk++)
                r4[kk] = *(const float4*)(B + (size_t)(k0 + skb + kk) * N + col0 + snb);
#pragma unroll
            for (int n = 0; n < 4; n++) {
                s16x4 w;
                w[0] = f2bf((&r4[0].x)[n]); w[1] = f2bf((&r4[1].x)[n]);
                w[2] = f2bf((&r4[2].x)[n]); w[3] = f2bf((&r4[3].x)[n]);
                *(s16x4*)&Bs[snb + n][skb] = w;
            }
        }
        __syncthreads();
#pragma unroll
        for (int kk = 0; kk < 64; kk += 32) {
            s16x8 a[4], b[2];
#pragma unroll
            for (int mi = 0; mi < 4; mi++) a[mi] = *(const s16x8*)&As[wm * 64 + mi * 16 + li][kk + g * 8];
#pragma unroll
            for (int ni = 0; ni < 2; ni++) b[ni] = *(const s16x8*)&Bs[wn * 32 + ni * 16 + li][kk + g * 8];
#pragma unroll
            for (int mi = 0; mi < 4; mi++)
#pragma unroll
                for (int ni = 0; ni < 2; ni++)
                    acc[mi][ni] = __builtin_amdgcn_mfma_f32_16x16x32_bf16(a[mi], b[ni], acc[mi][ni], 0, 0, 0);
        }
        __syncthreads();
    }
#pragma unroll
    for (int mi = 0; mi < 4; mi++)
#pragma unroll
        for (int ni = 0; ni < 2; ni++) {
            int gc = col0 + wn * 32 + ni * 16 + li;
#pragma unroll
            for (int r = 0; r < 4; r++) {
                int gr = wm * 64 + mi * 16 + g * 4 + r;
                if (gr < nrows) C[(size_t)gr * N + gc] = acc[mi][ni][r];
            }
        }
}

// ---------------- RoPE + build qf/kf/v as split planes ----------------
__global__ void prep_qkv_kernel(const float* __restrict__ q, const float* __restrict__ kva,
                                const float* __restrict__ kv, const int* __restrict__ positions,
                                short* __restrict__ qfh, short* __restrict__ qfl,
                                short* __restrict__ kfh, short* __restrict__ kfl,
                                short* __restrict__ vbh, short* __restrict__ vbl) {
    int t = blockIdx.x;
    __shared__ float cs[16], sn[16];
    if (threadIdx.x < 16) {
        float invf = powf(10000.f, -(float)(2 * threadIdx.x) / 32.f);
        float fr = (float)positions[t] * invf;
        cs[threadIdx.x] = cosf(fr);
        sn[threadIdx.x] = sinf(fr);
    }
    __syncthreads();
    for (int i = threadIdx.x; i < NH * QKD; i += blockDim.x) {
        int h = i / QKD, d = i % QKD;
        float val;
        if (d < 64) val = q[(size_t)t * 1536 + h * QKD + d];
        else {
            int r = d - 64, pr = r >> 1;
            float x1 = q[(size_t)t * 1536 + h * QKD + 64 + 2 * pr];
            float x2 = q[(size_t)t * 1536 + h * QKD + 64 + 2 * pr + 1];
            val = (r & 1) ? (x1 * sn[pr] + x2 * cs[pr]) : (x1 * cs[pr] - x2 * sn[pr]);
        }
        short hh = f2bf(val);
        qfh[(size_t)t * 1536 + i] = hh;
        qfl[(size_t)t * 1536 + i] = f2bf(val - bf2f(hh));
    }
    for (int i = threadIdx.x; i < NH * QKD; i += blockDim.x) {
        int h = i / QKD, d = i % QKD;
        float val;
        if (d < 64) val = kv[(size_t)t * 2048 + h * 128 + d];
        else {
            int r = d - 64, pr = r >> 1;
            float x1 = kva[(size_t)t * 288 + 256 + 2 * pr];
            float x2 = kva[(size_t)t * 288 + 256 + 2 * pr + 1];
            val = (r & 1) ? (x1 * sn[pr] + x2 * cs[pr]) : (x1 * cs[pr] - x2 * sn[pr]);
        }
        short hh = f2bf(val);
        kfh[(size_t)t * 1536 + i] = hh;
        kfl[(size_t)t * 1536 + i] = f2bf(val - bf2f(hh));
    }
    for (int i = threadIdx.x; i < NH * VD; i += blockDim.x) {
        int h = i / VD, d = i % VD;
        float val = kv[(size_t)t * 2048 + h * 128 + 64 + d];
        short hh = f2bf(val);
        vbh[(size_t)t * 1024 + i] = hh;
        vbl[(size_t)t * 1024 + i] = f2bf(val - bf2f(hh));
    }
}

// =====================================================================
// MFMA flash attention (verified; reads/writes bf16 planes)
// =====================================================================
__global__ __launch_bounds__(256) void attn_mfma_kernel(const short* __restrict__ qfh, const short* __restrict__ qfl,
                                                        const short* __restrict__ kfh, const short* __restrict__ kfl,
                                                        const short* __restrict__ vbh, const short* __restrict__ vbl,
                                                        short* __restrict__ obh, short* __restrict__ obl) {
    __shared__ short K_hi[64][104], K_lo[64][104];
    __shared__ short Vt_hi[64][72], Vt_lo[64][72];
    __shared__ short P_hi[4][16][72], P_lo[4][16][72];
    const int qt = blockIdx.x, h = blockIdx.y;
    const int tid = threadIdx.x, lane = tid & 63, w = tid >> 6;
    const int g = lane >> 4, li = lane & 15;

    s16x8 q_hi[3], q_lo[3];
    {
        const short* qb_h = qfh + (size_t)(qt * 64 + w * 16 + li) * 1536 + h * QKD;
        const short* qb_l = qfl + (size_t)(qt * 64 + w * 16 + li) * 1536 + h * QKD;
#pragma unroll
        for (int ks = 0; ks < 3; ks++) {
            q_hi[ks] = *(const s16x8*)(qb_h + ks * 32 + g * 8);
            q_lo[ks] = *(const s16x8*)(qb_l + ks * 32 + g * 8);
        }
    }

    f32x4 acc_o[4];
#pragma unroll
    for (int nc = 0; nc < 4; nc++)
#pragma unroll
        for (int r = 0; r < 4; r++) acc_o[nc][r] = 0.f;
    float m4[4] = {-1e30f, -1e30f, -1e30f, -1e30f};
    float l4[4] = {0.f, 0.f, 0.f, 0.f};
    const float scale = 0.102062072616f;

    for (int kt = 0; kt <= qt; kt++) {
#pragma unroll
        for (int it = 0; it < 3; it++) {
            int cid = it * 256 + tid;
            int key = cid / 12, c = cid % 12;
            *(s16x8*)&K_hi[key][c * 8] = *(const s16x8*)&kfh[(size_t)(kt * 64 + key) * 1536 + h * QKD + c * 8];
            *(s16x8*)&K_lo[key][c * 8] = *(const s16x8*)&kfl[(size_t)(kt * 64 + key) * 1536 + h * QKD + c * 8];
        }
#pragma unroll
        for (int it = 0; it < 2; it++) {
            int cid = it * 256 + tid;
            int key = cid >> 3, vc = cid & 7;
            s16x8 vh = *(const s16x8*)&vbh[(size_t)(kt * 64 + key) * 1024 + h * VD + vc * 8];
            s16x8 vl = *(const s16x8*)&vbl[(size_t)(kt * 64 + key) * 1024 + h * VD + vc * 8];
#pragma unroll
            for (int j = 0; j < 8; j++) {
                Vt_hi[vc * 8 + j][key] = vh[j];
                Vt_lo[vc * 8 + j][key] = vl[j];
            }
        }
        __syncthreads();

        f32x4 acc_s[4];
#pragma unroll
        for (int kc = 0; kc < 4; kc++)
#pragma unroll
            for (int r = 0; r < 4; r++) acc_s[kc][r] = 0.f;
#pragma unroll
        for (int ks = 0; ks < 3; ks++) {
#pragma unroll
            for (int kc = 0; kc < 4; kc++) {
                s16x8 kh = *(const s16x8*)&K_hi[kc * 16 + li][ks * 32 + g * 8];
                s16x8 kl = *(const s16x8*)&K_lo[kc * 16 + li][ks * 32 + g * 8];
                acc_s[kc] = __builtin_amdgcn_mfma_f32_16x16x32_bf16(q_hi[ks], kh, acc_s[kc], 0, 0, 0);
                acc_s[kc] = __builtin_amdgcn_mfma_f32_16x16x32_bf16(q_lo[ks], kh, acc_s[kc], 0, 0, 0);
                acc_s[kc] = __builtin_amdgcn_mfma_f32_16x16x32_bf16(q_hi[ks], kl, acc_s[kc], 0, 0, 0);
            }
        }
#pragma unroll
        for (int kc = 0; kc < 4; kc++)
#pragma unroll
            for (int r = 0; r < 4; r++) acc_s[kc][r] *= scale;
        if (kt == qt) {
#pragma unroll
            for (int kc = 0; kc < 4; kc++) {
                int key = kt * 64 + kc * 16 + li;
#pragma unroll
                for (int r = 0; r < 4; r++) {
                    int qr = qt * 64 + w * 16 + g * 4 + r;
                    if (key > qr) acc_s[kc][r] = -1e30f;
                }
            }
        }
        float tm4[4];
#pragma unroll
        for (int r = 0; r < 4; r++)
            tm4[r] = fmaxf(fmaxf(acc_s[0][r], acc_s[1][r]), fmaxf(acc_s[2][r], acc_s[3][r]));
#pragma unroll
        for (int off = 1; off < 16; off <<= 1)
#pragma unroll
            for (int r = 0; r < 4; r++) tm4[r] = fmaxf(tm4[r], __shfl_xor(tm4[r], off));
        float alpha[4];
#pragma unroll
        for (int r = 0; r < 4; r++) {
            float mn = fmaxf(m4[r], tm4[r]);
            alpha[r] = __expf(m4[r] - mn);
            m4[r] = mn;
        }
        float rs[4] = {0.f, 0.f, 0.f, 0.f};
#pragma unroll
        for (int kc = 0; kc < 4; kc++)
#pragma unroll
            for (int r = 0; r < 4; r++) {
                float p = __expf(acc_s[kc][r] - m4[r]);
                rs[r] += p;
                short hh = f2bf(p);
                P_hi[w][g * 4 + r][kc * 16 + li] = hh;
                P_lo[w][g * 4 + r][kc * 16 + li] = f2bf(p - bf2f(hh));
            }
#pragma unroll
        for (int off = 1; off < 16; off <<= 1)
#pragma unroll
            for (int r = 0; r < 4; r++) rs[r] += __shfl_xor(rs[r], off);
#pragma unroll
        for (int r = 0; r < 4; r++) l4[r] = l4[r] * alpha[r] + rs[r];
#pragma unroll
        for (int nc = 0; nc < 4; nc++)
#pragma unroll
            for (int r = 0; r < 4; r++) acc_o[nc][r] *= alpha[r];
#pragma unroll
        for (int ks = 0; ks < 2; ks++) {
            s16x8 ph = *(const s16x8*)&P_hi[w][li][ks * 32 + g * 8];
            s16x8 pl = *(const s16x8*)&P_lo[w][li][ks * 32 + g * 8];
#pragma unroll
            for (int nc = 0; nc < 4; nc++) {
                s16x8 vh = *(const s16x8*)&Vt_hi[nc * 16 + li][ks * 32 + g * 8];
                s16x8 vl = *(const s16x8*)&Vt_lo[nc * 16 + li][ks * 32 + g * 8];
                acc_o[nc] = __builtin_amdgcn_mfma_f32_16x16x32_bf16(ph, vh, acc_o[nc], 0, 0, 0);
                acc_o[nc] = __builtin_amdgcn_mfma_f32_16x16x32_bf16(pl, vh, acc_o[nc], 0, 0, 0);
                acc_o[nc] = __builtin_amdgcn_mfma_f32_16x16x32_bf16(ph, vl, acc_o[nc], 0, 0, 0);
            }
        }
        __syncthreads();
    }
    float inv[4];
#pragma unroll
    for (int r = 0; r < 4; r++) inv[r] = 1.f / l4[r];
#pragma unroll
    for (int nc = 0; nc < 4; nc++)
#pragma unroll
        for (int r = 0; r < 4; r++) {
            float o = acc_o[nc][r] * inv[r];
            size_t idx = (size_t)(qt * 64 + w * 16 + g * 4 + r) * 1024 + h * VD + nc * 16 + li;
            short hh = f2bf(o);
            obh[idx] = hh;
            obl[idx] = f2bf(o - bf2f(hh));
        }
}

// ---------------- fused resid-add + post-rmsnorm + routing ----------------
__global__ __launch_bounds__(256) void fused_post_attn(float* __restrict__ x0, const float* __restrict__ att,
                                                       const float* __restrict__ w, const float* __restrict__ gate_w,
                                                       const float* __restrict__ gate_bias,
                                                       short* __restrict__ h2bf, int* __restrict__ topidx,
                                                       float* __restrict__ topw) {
    int t = blockIdx.x;
    float resid[8];
    float ss = 0.f;
#pragma unroll
    for (int j = 0; j < 8; j++) {
        int i = threadIdx.x + j * 256;
        float v = x0[(size_t)t * HDIM + i] + att[(size_t)t * HDIM + i];
        resid[j] = v;
        x0[(size_t)t * HDIM + i] = v;
        ss += v * v;
    }
    float r = rsqrtf(block_sum(ss) / HDIM + EPSF);
    float acc[8] = {0.f, 0.f, 0.f, 0.f, 0.f, 0.f, 0.f, 0.f};
#pragma unroll
    for (int j = 0; j < 8; j++) {
        int i = threadIdx.x + j * 256;
        float v = resid[j] * r * w[i];
        h2bf[(size_t)t * HDIM + i] = f2bf(v);
        const float* gw = gate_w + (size_t)i * 8;
        float4 g0 = *(const float4*)gw;
        float4 g1 = *(const float4*)(gw + 4);
        acc[0] = fmaf(v, g0.x, acc[0]); acc[1] = fmaf(v, g0.y, acc[1]);
        acc[2] = fmaf(v, g0.z, acc[2]); acc[3] = fmaf(v, g0.w, acc[3]);
        acc[4] = fmaf(v, g1.x, acc[4]); acc[5] = fmaf(v, g1.y, acc[5]);
        acc[6] = fmaf(v, g1.z, acc[6]); acc[7] = fmaf(v, g1.w, acc[7]);
    }
    __shared__ float logits[8];
    for (int e = 0; e < 8; e++) {
        float s = block_sum(acc[e]);
        if (threadIdx.x == 0) logits[e] = s;
    }
    __syncthreads();
    if (threadIdx.x == 0) {
        float sig[8], sc[8];
        for (int e = 0; e < 8; e++) {
            sig[e] = 1.f / (1.f + expf(-logits[e]));
            sc[e] = sig[e] + gate_bias[e];
        }
        int i0 = 0;
        for (int e = 1; e < 8; e++) if (sc[e] > sc[i0]) i0 = e;
        int i1 = -1;
        for (int e = 0; e < 8; e++) if (e != i0 && (i1 < 0 || sc[e] > sc[i1])) i1 = e;
        float w0 = sig[i0], w1 = sig[i1], s = w0 + w1 + 1e-20f;
        topidx[t * 2 + 0] = i0; topidx[t * 2 + 1] = i1;
        topw[t * 2 + 0] = w0 / s; topw[t * 2 + 1] = w1 / s;
    }
}

// ---------------- counting sort + tile map ----------------
__global__ void sort_kernel(const int* __restrict__ topidx, int* __restrict__ sorted_t,
                            int* __restrict__ slotpos, int4* __restrict__ tilemap) {
    __shared__ int counts[8], offs[9];
    int wid = threadIdx.x >> 6, lane = threadIdx.x & 63;
    int cnt = 0;
    for (int base = 0; base < 2 * T_; base += 64) {
        int e = topidx[base + lane];
        unsigned long long m = __ballot(e == wid);
        cnt += __popcll(m);
    }
    if (lane == 0) counts[wid] = cnt;
    __syncthreads();
    if (threadIdx.x == 0) {
        offs[0] = 0;
        for (int e = 0; e < 8; e++) offs[e + 1] = offs[e] + counts[e];
    }
    __syncthreads();
    int pos = offs[wid];
    for (int base = 0; base < 2 * T_; base += 64) {
        int sl = base + lane;
        int e = topidx[sl];
        bool match = (e == wid);
        unsigned long long m = __ballot(match);
        if (match) {
            int before = __popcll(m & ((1ull << lane) - 1ull));
            int pp = pos + before;
            sorted_t[pp] = sl >> 1;
            slotpos[sl] = pp;
        }
        pos += __popcll(m);
    }
    __syncthreads();
    if (threadIdx.x == 0) {
        int nt = 0;
        for (int e = 0; e < 8; e++) {
            int c = counts[e], o = offs[e];
            for (int r = 0; r < c; r += 128) {
                tilemap[nt] = make_int4(e, o + r, min(128, c - r), 0);
                nt++;
            }
        }
        for (int i = nt; i < MAXTILES; i++) tilemap[i] = make_int4(0, 0, 0, 0);
    }
}

// ---------------- gather h2bf rows (bf16) ----------------
__global__ void gather_bf16_kernel(const short* __restrict__ h2bf, const int* __restrict__ sorted_t,
                                   short* __restrict__ gout) {
    int pp = blockIdx.x;
    int t = sorted_t[pp];
    const s16x8* src = (const s16x8*)(h2bf + (size_t)t * HDIM);
    s16x8* dst = (s16x8*)(gout + (size_t)pp * HDIM);
    dst[threadIdx.x] = src[threadIdx.x];
}

// ---------------- silu(g)*u -> bf16 (shared MLP) ----------------
__global__ void silu_mul_bf16_kernel(const float* __restrict__ g, const float* __restrict__ u,
                                     short* __restrict__ outh, int n) {
    int stride = gridDim.x * blockDim.x;
    for (int i = blockIdx.x * blockDim.x + threadIdx.x; i < n; i += stride) {
        float x = g[i];
        outh[i] = f2bf((x / (1.f + expf(-x))) * u[i]);
    }
}

// ---------------- final combine -> f32 out ----------------
__global__ void final_kernel(const float* __restrict__ resid, const float* __restrict__ sho,
                             const float* __restrict__ md, const int* __restrict__ slotpos,
                             const float* __restrict__ topw, float* __restrict__ out) {
    int t = blockIdx.x;
    int p0 = slotpos[t * 2 + 0], p1 = slotpos[t * 2 + 1];
    float w0 = topw[t * 2 + 0] * 2.5f, w1 = topw[t * 2 + 1] * 2.5f;
    for (int c = threadIdx.x; c < HDIM; c += blockDim.x) {
        float v = resid[(size_t)t * HDIM + c] + sho[(size_t)t * HDIM + c]
                + w0 * md[(size_t)p0 * HDIM + c] + w1 * md[(size_t)p1 * HDIM + c];
        out[(size_t)t * HDIM + c] = v;
    }
}

// ---------------- launcher ----------------
extern "C" void kernel_launch(void* const* d_in, const int* in_sizes, int n_in,
                              void* d_out, int out_size, void* d_ws, size_t ws_size,
                              hipStream_t stream) {
    (void)in_sizes; (void)n_in; (void)out_size; (void)ws_size;
    const int*   input_ids = (const int*)d_in[0];
    const int*   positions = (const int*)d_in[1];
    const float* prev      = (const float*)d_in[2];
    const float* embed     = (const float*)d_in[3];
    const float* enorm_w   = (const float*)d_in[4];
    const float* hnorm_w   = (const float*)d_in[5];
    const float* eh_proj_w = (const float*)d_in[6];
    const float* in_ln_w   = (const float*)d_in[7];
    const float* post_ln_w = (const float*)d_in[8];
    const float* q_a_w     = (const float*)d_in[9];
    const float* q_a_ln_w  = (const float*)d_in[10];
    const float* q_b_w     = (const float*)d_in[11];
    const float* kv_a_w    = (const float*)d_in[12];
    const float* kv_a_ln_w = (const float*)d_in[13];
    const float* kv_b_w    = (const float*)d_in[14];
    const float* o_w       = (const float*)d_in[15];
    const float* gate_w    = (const float*)d_in[16];
    const float* gate_bias = (const float*)d_in[17];
    const float* exp_g     = (const float*)d_in[18];
    const float* exp_u     = (const float*)d_in[19];
    const float* exp_d     = (const float*)d_in[20];
    const float* sh_g      = (const float*)d_in[21];
    const float* sh_u      = (const float*)d_in[22];
    const float* sh_d      = (const float*)d_in[23];
    float* out = (float*)d_out;

    float* ws = (float*)d_ws;
    short* catH  = (short*)(ws + OF_CATH);
    short* catL  = (short*)(ws + OF_CATL);
    short* gact  = (short*)(ws + OF_GACT);
    float* x0    = ws + OF_X0;
    short* mact  = (short*)(ws + OF_MACT);
    short* hH    = (short*)(ws + OF_HH);
    short* hL    = (short*)(ws + OF_HL);
    float* sho   = ws + OF_SHO;
    float* qraw  = ws + OF_QRAW;
    float* qbuf  = ws + OF_QBUF;
    float* kva   = ws + OF_KVA;
    float* kvbuf = ws + OF_KVBUF;
    float* md    = ws + OF_MD;
    short* qaH   = (short*)(ws + OF_QAH);
    short* qaL   = (short*)(ws + OF_QAL);
    short* kvcnH = (short*)(ws + OF_KVCNH);
    short* kvcnL = (short*)(ws + OF_KVCNL);
    short* qfH   = (short*)(ws + OF_QFH);
    short* qfL   = (short*)(ws + OF_QFL);
    short* kfH   = (short*)(ws + OF_KFH);
    short* kfL   = (short*)(ws + OF_KFL);
    short* vbH   = (short*)(ws + OF_VBH);
    short* vbL   = (short*)(ws + OF_VBL);
    short* obH   = (short*)(ws + OF_OBH);
    short* obL   = (short*)(ws + OF_OBL);
    float* att   = ws + OF_ATT;
    float* sg    = ws + OF_SG;
    float* su    = ws + OF_SU;
    short* h2bf  = (short*)(ws + OF_H2BF);
    short* sgact = (short*)(ws + OF_SGACT);
    int*   ri       = (int*)(ws + OF_ROUT);
    int*   topidx   = ri;
    int*   sorted_t = ri + 2048;
    int*   slotpos  = ri + 4096;
    int4*  tilemap  = (int4*)(ri + 6144);
    float* topw     = (float*)(ri + 6144 + 4 * MAXTILES);
    short* ehTH  = (short*)(ws + OF_EHTH);
    short* ehTL  = (short*)(ws + OF_EHTL);
    short* qaTH  = (short*)(ws + OF_QATH);
    short* qaTL  = (short*)(ws + OF_QATL);
    short* qbTH  = (short*)(ws + OF_QBTH);
    short* qbTL  = (short*)(ws + OF_QBTL);
    short* kvaTH = (short*)(ws + OF_KVATH);
    short* kvaTL = (short*)(ws + OF_KVATL);
    short* kvbTH = (short*)(ws + OF_KVBTH);
    short* kvbTL = (short*)(ws + OF_KVBTL);
    short* owTH  = (short*)(ws + OF_OWTH);
    short* owTL  = (short*)(ws + OF_OWTL);
    short* shgT  = (short*)(ws + OF_SHGT);
    short* shuT  = (short*)(ws + OF_SHUT);
    short* shdT  = (short*)(ws + OF_SHDT);

    dim3 blk(256);

    // 0. weight transpose+split (kv_a grid y: 6->5, fixes 320-row plane overflow race)
    transpose_split_kernel<<<dim3(64, 32), blk, 0, stream>>>(eh_proj_w, ehTH, ehTL, 4096, 2048, 1);
    transpose_split_kernel<<<dim3(32, 8), blk, 0, stream>>>(q_a_w, qaTH, qaTL, 2048, 512, 1);
    transpose_split_kernel<<<dim3(8, 24), blk, 0, stream>>>(q_b_w, qbTH, qbTL, 512, 1536, 1);
    transpose_split_kernel<<<dim3(32, 5), blk, 0, stream>>>(kv_a_w, kvaTH, kvaTL, 2048, 288, 1);
    transpose_split_kernel<<<dim3(4, 32), blk, 0, stream>>>(kv_b_w, kvbTH, kvbTL, 256, 2048, 1);
    transpose_split_kernel<<<dim3(16, 32), blk, 0, stream>>>(o_w, owTH, owTL, 1024, 2048, 1);
    transpose_split_kernel<<<dim3(32, 16), blk, 0, stream>>>(sh_g, shgT, nullptr, 2048, 1024, 0);
    transpose_split_kernel<<<dim3(32, 16), blk, 0, stream>>>(sh_u, shuT, nullptr, 2048, 1024, 0);
    transpose_split_kernel<<<dim3(16, 32), blk, 0, stream>>>(sh_d, shdT, nullptr, 1024, 2048, 0);

    // 1. embed + rmsnorm + concat
    embed_cat_kernel<<<T_, blk, 0, stream>>>(input_ids, embed, enorm_w, prev, hnorm_w, catH, catL);
    // 2. x0 = cat @ eh_proj
    gemm_planes<true><<<dim3(32, 8), blk, 0, stream>>>(catH, catL, ehTH, ehTL, x0, T_, 2048, 4096);
    // 3. h = rmsnorm(x0)
    rmsnorm_kernel<<<T_, blk, 0, stream>>>(x0, 2048, 2048, in_ln_w, nullptr, hH, hL, 2048);
    // 4. q_a
    gemm_planes<true><<<dim3(8, 8), blk, 0, stream>>>(hH, hL, qaTH, qaTL, qraw, T_, 512, 2048);
    rmsnorm_kernel<<<T_, blk, 0, stream>>>(qraw, 512, 512, q_a_ln_w, nullptr, qaH, qaL, 512);
    // 5. q = qa @ q_b
    gemm_planes<true><<<dim3(24, 8), blk, 0, stream>>>(qaH, qaL, qbTH, qbTL, qbuf, T_, 1536, 512);
    // 6. kva = h @ kv_a
    gemm_planes<true><<<dim3(5, 8), blk, 0, stream>>>(hH, hL, kvaTH, kvaTL, kva, T_, 288, 2048);
    // 7. kvcn
    rmsnorm_kernel<<<T_, blk, 0, stream>>>(kva, 288, 256, kv_a_ln_w, nullptr, kvcnH, kvcnL, 256);
    // 8. kv = kvcn @ kv_b
    gemm_planes<true><<<dim3(32, 8), blk, 0, stream>>>(kvcnH, kvcnL, kvbTH, kvbTL, kvbuf, T_, 2048, 256);
    // 9. rope + planes
    prep_qkv_kernel<<<T_, blk, 0, stream>>>(qbuf, kva, kvbuf, positions, qfH, qfL, kfH, kfL, vbH, vbL);
    // 10. flash attention
    attn_mfma_kernel<<<dim3(T_ / 64, NH), blk, 0, stream>>>(qfH, qfL, kfH, kfL, vbH, vbL, obH, obL);
    // 11. attn_out = ob @ o_w
    gemm_planes<true><<<dim3(32, 8), blk, 0, stream>>>(obH, obL, owTH, owTL, att, T_, 2048, 1024);
    // 12-14. fused resid + rmsnorm + routing
    fused_post_attn<<<T_, blk, 0, stream>>>(x0, att, post_ln_w, gate_w, gate_bias, h2bf, topidx, topw);
    // 15. sort
    sort_kernel<<<1, 512, 0, stream>>>(topidx, sorted_t, slotpos, tilemap);
    // 16. gather (bf16)
    gather_bf16_kernel<<<2 * T_, blk, 0, stream>>>(h2bf, sorted_t, gact);
    // 17+18. MoE gate+up fused with silu -> mact (bf16)
    moe_gateup<<<dim3(16, MAXTILES), blk, 0, stream>>>(gact, exp_g, exp_u, mact, tilemap, 2048, 1024);
    // 19. MoE down (bf16 A)
    moe_down<<<dim3(32, MAXTILES), blk, 0, stream>>>(mact, exp_d, md, tilemap, 1024, 2048);
    // 20. shared MLP
    gemm_planes<false><<<dim3(16, 8), blk, 0, stream>>>(h2bf, h2bf, shgT, shgT, sg, T_, 1024, 2048);
    gemm_planes<false><<<dim3(16, 8), blk, 0, stream>>>(h2bf, h2bf, shuT, shuT, su, T_, 1024, 2048);
    silu_mul_bf16_kernel<<<1024, blk, 0, stream>>>(sg, su, sgact, T_ * 1024);
    gemm_planes<false><<<dim3(32, 8), blk, 0, stream>>>(sgact, sgact, shdT, shdT, sho, T_, 2048, 1024);
    // 21. final combine
    final_kernel<<<T_, blk, 0, stream>>>(x0, sho, md, slotpos, topw, out);
}

// Round 10
// 634.342 us; speedup vs baseline: 1.5157x; 1.1764x over previous
//
#include <hip/hip_runtime.h>
#include <hip/hip_bf16.h>
#include <math.h>

constexpr int T_ = 1024;
constexpr int HDIM = 2048;
constexpr int NH = 16;
constexpr int QKD = 96;
constexpr int VD = 64;
constexpr int MAXTILES = 32;   // <=24 expert tiles + 8 shared tiles
constexpr float EPSF = 1e-6f;

using f32x4 = __attribute__((ext_vector_type(4))) float;
using s16x8 = __attribute__((ext_vector_type(8))) short;
using s16x4 = __attribute__((ext_vector_type(4))) short;

// ---------------- workspace layout (float offsets; ws is ~1 GB) ----------------
constexpr size_t OF_CATH  = 0;                 // bf16 T*4096
constexpr size_t OF_CATL  = 2097152;
constexpr size_t OF_GACT  = 0;                 // bf16 3072*2048 (alias cat planes; disjoint lifetime)
constexpr size_t OF_X0    = 4194304;           // f32 T*2048
constexpr size_t OF_MACT  = 6291456;           // bf16 3072*1024
constexpr size_t OF_HH    = 8388608;           // bf16 T*2048
constexpr size_t OF_HL    = 9437184;
constexpr size_t OF_QRAW  = 10485760;          // f32 T*512
constexpr size_t OF_QBUF  = 11010048;          // f32 T*1536
constexpr size_t OF_KVA   = 12582912;          // f32 T*288
constexpr size_t OF_KVBUF = 12877824;          // f32 T*2048
constexpr size_t OF_QAH   = 14974976;          // bf16 T*512
constexpr size_t OF_QAL   = 15237120;
constexpr size_t OF_KVCNH = 15499264;          // bf16 T*256
constexpr size_t OF_KVCNL = 15630336;
constexpr size_t OF_QFH   = 15761408;          // bf16 T*1536
constexpr size_t OF_QFL   = 16547840;
constexpr size_t OF_KFH   = 17334272;
constexpr size_t OF_KFL   = 18120704;
constexpr size_t OF_VBH   = 18907136;          // bf16 T*1024
constexpr size_t OF_VBL   = 19431424;
constexpr size_t OF_OBH   = 19955712;          // bf16 T*1024
constexpr size_t OF_OBL   = 20480000;
constexpr size_t OF_ATT   = 21004288;          // f32 T*2048
constexpr size_t OF_H2BF  = 23101440;          // bf16 T*2048
constexpr size_t OF_ROUT  = 24674304;          // ints (8320 used, 8448 available)
// weight planes (bf16)
constexpr size_t OF_EHTH  = 24682752;          // [2048][4096]
constexpr size_t OF_EHTL  = 28877056;
constexpr size_t OF_QATH  = 33071360;          // [512][2048]
constexpr size_t OF_QATL  = 33595648;
constexpr size_t OF_QBTH  = 34119936;          // [1536][512]
constexpr size_t OF_QBTL  = 34513152;
constexpr size_t OF_KVATH = 34906368;          // [320][2048] (288 used)
constexpr size_t OF_KVATL = 35234048;
constexpr size_t OF_KVBTH = 35561728;          // [2048][256]
constexpr size_t OF_KVBTL = 35823872;
constexpr size_t OF_OWTH  = 36086016;          // [2048][1024]
constexpr size_t OF_OWTL  = 37134592;
constexpr size_t OF_MD    = 38183168;          // f32 3072*2048 (ends 44474624 floats = 178 MB)

// ---------------- helpers ----------------
__device__ __forceinline__ short f2bf(float f) {
    union { float f; unsigned u; } x; x.f = f;
    unsigned r = x.u + 0x7fffu + ((x.u >> 16) & 1u);
    return (short)(r >> 16);
}
__device__ __forceinline__ float bf2f(short h) {
    union { unsigned u; float f; } x; x.u = ((unsigned)(unsigned short)h) << 16; return x.f;
}
// LDS swizzle (plane GEMM): row stride 64 shorts; chunk ^= row&7
__device__ __forceinline__ int swz(int r, int k) {
    return (r << 6) + ((((k >> 3) ^ (r & 7)) << 3) | (k & 7));
}
// async global->LDS, 16 B per lane; LDS dest = wave-uniform base + lane*16
__device__ __forceinline__ void gload16(const void* g, void* l) {
    __builtin_amdgcn_global_load_lds((__attribute__((address_space(1))) void*)g,
                                     (__attribute__((address_space(3))) void*)l, 16, 0, 0);
}

__device__ __forceinline__ float block_sum(float v) {
    __shared__ float sbuf[9];
    int lane = threadIdx.x & 63;
    int wid  = threadIdx.x >> 6;
#pragma unroll
    for (int off = 32; off > 0; off >>= 1) v += __shfl_down(v, off);
    __syncthreads();
    if (lane == 0) sbuf[wid] = v;
    __syncthreads();
    if (threadIdx.x == 0) {
        float s = 0.f;
        int nw = blockDim.x >> 6;
        for (int i = 0; i < nw; i++) s += sbuf[i];
        sbuf[8] = s;
    }
    __syncthreads();
    return sbuf[8];
}

// ---------------- weight transpose + split ----------------
__global__ void transpose_split_kernel(const float* __restrict__ W, short* __restrict__ Whi,
                                       short* __restrict__ Wlo, int K, int N, int split) {
    __shared__ float tile[64][65];
    int k0 = blockIdx.x * 64, n0 = blockIdx.y * 64;
    int tn = threadIdx.x & 63;
    int tk4 = threadIdx.x >> 6;
#pragma unroll 4
    for (int i = 0; i < 16; i++) {
        int kk = tk4 * 16 + i;
        int gn = n0 + tn;
        tile[kk][tn] = (gn < N) ? W[(size_t)(k0 + kk) * N + gn] : 0.f;
    }
    __syncthreads();
    int on = threadIdx.x >> 2;
    int oc = threadIdx.x & 3;
#pragma unroll 4
    for (int i = 0; i < 16; i++) {
        int kk = oc * 16 + i;
        float v = tile[kk][on];
        short hh = f2bf(v);
        size_t o = (size_t)(n0 + on) * K + k0 + kk;
        Whi[o] = hh;
        if (split) Wlo[o] = f2bf(v - bf2f(hh));
    }
}

// ---------------- embedding + rmsnorm + concat -> split planes ----------------
__global__ void embed_cat_kernel(const int* __restrict__ ids, const float* __restrict__ embed,
                                 const float* __restrict__ enorm, const float* __restrict__ prev,
                                 const float* __restrict__ hnorm, short* __restrict__ ch,
                                 short* __restrict__ cl) {
    int t = blockIdx.x;
    const float* e = embed + (size_t)ids[t] * HDIM;
    float ss = 0.f;
    for (int i = threadIdx.x; i < HDIM; i += blockDim.x) { float v = e[i]; ss += v * v; }
    float r = rsqrtf(block_sum(ss) / HDIM + EPSF);
    for (int i = threadIdx.x; i < HDIM; i += blockDim.x) {
        float v = e[i] * r * enorm[i];
        short hh = f2bf(v);
        ch[(size_t)t * 4096 + i] = hh;
        cl[(size_t)t * 4096 + i] = f2bf(v - bf2f(hh));
    }
    const float* p = prev + (size_t)t * HDIM;
    ss = 0.f;
    for (int i = threadIdx.x; i < HDIM; i += blockDim.x) { float v = p[i]; ss += v * v; }
    r = rsqrtf(block_sum(ss) / HDIM + EPSF);
    for (int i = threadIdx.x; i < HDIM; i += blockDim.x) {
        float v = p[i] * r * hnorm[i];
        short hh = f2bf(v);
        ch[(size_t)t * 4096 + 2048 + i] = hh;
        cl[(size_t)t * 4096 + 2048 + i] = f2bf(v - bf2f(hh));
    }
}

// ---------------- rmsnorm (f32 / hi / lo outputs) ----------------
__global__ void rmsnorm_kernel(const float* __restrict__ in, int in_stride, int width,
                               const float* __restrict__ w, float* __restrict__ outf,
                               short* __restrict__ outh, short* __restrict__ outl, int out_stride) {
    int t = blockIdx.x;
    const float* x = in + (size_t)t * in_stride;
    float ss = 0.f;
    for (int i = threadIdx.x; i < width; i += blockDim.x) { float v = x[i]; ss += v * v; }
    float r = rsqrtf(block_sum(ss) / width + EPSF);
    size_t ob = (size_t)t * out_stride;
    for (int i = threadIdx.x; i < width; i += blockDim.x) {
        float v = x[i] * r * w[i];
        if (outf) outf[ob + i] = v;
        if (outh) {
            short hh = f2bf(v);
            outh[ob + i] = hh;
            if (outl) outl[ob + i] = f2bf(v - bf2f(hh));
        }
    }
}

// =====================================================================
// Plane GEMM: BM=128 BN=64 BK=64, swizzled LDS (reads), staging via
// global_load_lds with inverse-swizzled per-lane global source (linear LDS
// dest). Compute identical to round-9 verified version.
// =====================================================================
template<bool SPLIT>
__global__ __launch_bounds__(256) void gemm_planes(const short* __restrict__ Ahi, const short* __restrict__ Alo,
                                                   const short* __restrict__ Bhi, const short* __restrict__ Blo,
                                                   float* __restrict__ C, int M, int N, int K) {
    __shared__ short As[SPLIT ? 2 : 1][128 * 64];
    __shared__ short Bs[SPLIT ? 2 : 1][64 * 64];
    const int tid = threadIdx.x;
    const int lane = tid & 63, wid = tid >> 6;
    const int g = lane >> 4, li = lane & 15;
    const int wm = wid >> 1, wn = wid & 1;
    const int row0 = blockIdx.y * 128, col0 = blockIdx.x * 64;

    f32x4 acc[4][2];
#pragma unroll
    for (int mi = 0; mi < 4; mi++)
#pragma unroll
        for (int ni = 0; ni < 2; ni++)
#pragma unroll
            for (int r = 0; r < 4; r++) acc[mi][ni][r] = 0.f;

    for (int k0 = 0; k0 < K; k0 += 64) {
        // ---- A: 1024 chunks; 16 instr/plane, 4 per wave; slot cid holds (r=cid>>3, c=(cid&7)^(r&7))
#pragma unroll
        for (int j = 0; j < 4; j++) {
            int blkI = wid * 4 + j;
            int cid = blkI * 64 + lane;
            int r = cid >> 3, c = (cid & 7) ^ (r & 7);
            const short* gh = &Ahi[(size_t)(row0 + r) * K + k0 + c * 8];
            gload16(gh, &As[0][blkI * 512]);
            if constexpr (SPLIT)
                gload16(&Alo[(size_t)(row0 + r) * K + k0 + c * 8], &As[1][blkI * 512]);
        }
        // ---- B: 512 chunks; 8 instr/plane, 2 per wave
#pragma unroll
        for (int j = 0; j < 2; j++) {
            int blkI = wid * 2 + j;
            int cid = blkI * 64 + lane;
            int r = cid >> 3, c = (cid & 7) ^ (r & 7);
            gload16(&Bhi[(size_t)(col0 + r) * K + k0 + c * 8], &Bs[0][blkI * 512]);
            if constexpr (SPLIT)
                gload16(&Blo[(size_t)(col0 + r) * K + k0 + c * 8], &Bs[1][blkI * 512]);
        }
        __syncthreads();   // compiler drains vmcnt before barrier
#pragma unroll
        for (int kk = 0; kk < 64; kk += 32) {
            s16x8 ah[4], bh[2];
#pragma unroll
            for (int mi = 0; mi < 4; mi++) ah[mi] = *(const s16x8*)&As[0][swz(wm * 64 + mi * 16 + li, kk + g * 8)];
#pragma unroll
            for (int ni = 0; ni < 2; ni++) bh[ni] = *(const s16x8*)&Bs[0][swz(wn * 32 + ni * 16 + li, kk + g * 8)];
            if constexpr (SPLIT) {
                s16x8 al[4], bl[2];
#pragma unroll
                for (int mi = 0; mi < 4; mi++) al[mi] = *(const s16x8*)&As[1][swz(wm * 64 + mi * 16 + li, kk + g * 8)];
#pragma unroll
                for (int ni = 0; ni < 2; ni++) bl[ni] = *(const s16x8*)&Bs[1][swz(wn * 32 + ni * 16 + li, kk + g * 8)];
#pragma unroll
                for (int mi = 0; mi < 4; mi++)
#pragma unroll
                    for (int ni = 0; ni < 2; ni++) {
                        acc[mi][ni] = __builtin_amdgcn_mfma_f32_16x16x32_bf16(ah[mi], bh[ni], acc[mi][ni], 0, 0, 0);
                        acc[mi][ni] = __builtin_amdgcn_mfma_f32_16x16x32_bf16(al[mi], bh[ni], acc[mi][ni], 0, 0, 0);
                        acc[mi][ni] = __builtin_amdgcn_mfma_f32_16x16x32_bf16(ah[mi], bl[ni], acc[mi][ni], 0, 0, 0);
                    }
            } else {
#pragma unroll
                for (int mi = 0; mi < 4; mi++)
#pragma unroll
                    for (int ni = 0; ni < 2; ni++)
                        acc[mi][ni] = __builtin_amdgcn_mfma_f32_16x16x32_bf16(ah[mi], bh[ni], acc[mi][ni], 0, 0, 0);
            }
        }
        __syncthreads();
    }
#pragma unroll
    for (int mi = 0; mi < 4; mi++)
#pragma unroll
        for (int ni = 0; ni < 2; ni++) {
            int gc = col0 + wn * 32 + ni * 16 + li;
            if (gc < N) {
#pragma unroll
                for (int r = 0; r < 4; r++) {
                    int gr = row0 + wm * 64 + mi * 16 + g * 4 + r;
                    C[(size_t)gr * N + gc] = acc[mi][ni][r];
                }
            }
        }
}

// =====================================================================
// MoE gate+up fused GEMM + silu epilogue; expert 8 == shared MLP.
// =====================================================================
__global__ __launch_bounds__(256) void moe_gateup(const short* __restrict__ Abase, const float* __restrict__ Wg,
                                                  const float* __restrict__ Wu, const float* __restrict__ Sg,
                                                  const float* __restrict__ Su, short* __restrict__ Cact,
                                                  const int4* __restrict__ tilemap, int K, int N) {
    int4 tm = tilemap[blockIdx.y];
    int nrows = tm.z;
    if (nrows == 0) return;
    const short* A = Abase + (size_t)tm.y * K;
    const float* Bg = (tm.x < 8) ? Wg + (size_t)tm.x * K * N : Sg;
    const float* Bu = (tm.x < 8) ? Wu + (size_t)tm.x * K * N : Su;

    alignas(16) __shared__ short As[128][72];
    alignas(16) __shared__ short Bgs[64][72];
    alignas(16) __shared__ short Bus[64][72];
    const int tid = threadIdx.x;
    const int lane = tid & 63, wid = tid >> 6;
    const int g = lane >> 4, li = lane & 15;
    const int wm = wid >> 1, wn = wid & 1;
    const int col0 = blockIdx.x * 64;

    f32x4 accg[4][2], accu[4][2];
#pragma unroll
    for (int mi = 0; mi < 4; mi++)
#pragma unroll
        for (int ni = 0; ni < 2; ni++)
#pragma unroll
            for (int r = 0; r < 4; r++) { accg[mi][ni][r] = 0.f; accu[mi][ni][r] = 0.f; }

    const int skb = (tid >> 4) << 2, snb = (tid & 15) << 2;

    for (int k0 = 0; k0 < K; k0 += 64) {
#pragma unroll
        for (int i = 0; i < 4; i++) {
            int cid = i * 256 + tid;
            int r = cid >> 3, c = cid & 7;
            s16x8 v;
            if (r < nrows) v = *(const s16x8*)&A[(size_t)r * K + k0 + c * 8];
            else {
#pragma unroll
                for (int j = 0; j < 8; j++) v[j] = 0;
            }
            *(s16x8*)&As[r][c * 8] = v;
        }
        {
            float4 rg[4], ru[4];
#pragma unroll
            for (int kk = 0; kk < 4; kk++) {
                rg[kk] = *(const float4*)(Bg + (size_t)(k0 + skb + kk) * N + col0 + snb);
                ru[kk] = *(const float4*)(Bu + (size_t)(k0 + skb + kk) * N + col0 + snb);
            }
#pragma unroll
            for (int n = 0; n < 4; n++) {
                s16x4 wg4, wu4;
                wg4[0] = f2bf((&rg[0].x)[n]); wg4[1] = f2bf((&rg[1].x)[n]);
                wg4[2] = f2bf((&rg[2].x)[n]); wg4[3] = f2bf((&rg[3].x)[n]);
                wu4[0] = f2bf((&ru[0].x)[n]); wu4[1] = f2bf((&ru[1].x)[n]);
                wu4[2] = f2bf((&ru[2].x)[n]); wu4[3] = f2bf((&ru[3].x)[n]);
                *(s16x4*)&Bgs[snb + n][skb] = wg4;
                *(s16x4*)&Bus[snb + n][skb] = wu4;
            }
        }
        __syncthreads();
#pragma unroll
        for (int kk = 0; kk < 64; kk += 32) {
            s16x8 a[4], bg2[2], bu2[2];
#pragma unroll
            for (int mi = 0; mi < 4; mi++) a[mi] = *(const s16x8*)&As[wm * 64 + mi * 16 + li][kk + g * 8];
#pragma unroll
            for (int ni = 0; ni < 2; ni++) {
                bg2[ni] = *(const s16x8*)&Bgs[wn * 32 + ni * 16 + li][kk + g * 8];
                bu2[ni] = *(const s16x8*)&Bus[wn * 32 + ni * 16 + li][kk + g * 8];
            }
#pragma unroll
            for (int mi = 0; mi < 4; mi++)
#pragma unroll
                for (int ni = 0; ni < 2; ni++) {
                    accg[mi][ni] = __builtin_amdgcn_mfma_f32_16x16x32_bf16(a[mi], bg2[ni], accg[mi][ni], 0, 0, 0);
                    accu[mi][ni] = __builtin_amdgcn_mfma_f32_16x16x32_bf16(a[mi], bu2[ni], accu[mi][ni], 0, 0, 0);
                }
        }
        __syncthreads();
    }
#pragma unroll
    for (int mi = 0; mi < 4; mi++)
#pragma unroll
        for (int ni = 0; ni < 2; ni++) {
            int gc = col0 + wn * 32 + ni * 16 + li;
#pragma unroll
            for (int r = 0; r < 4; r++) {
                int gr = wm * 64 + mi * 16 + g * 4 + r;
                if (gr < nrows) {
                    float x = accg[mi][ni][r], u = accu[mi][ni][r];
                    Cact[(size_t)(tm.y + gr) * N + gc] = f2bf((x / (1.f + expf(-x))) * u);
                }
            }
        }
}

// =====================================================================
// MoE down GEMM (expert 8 == shared down): A bf16 mact; out md f32.
// =====================================================================
__global__ __launch_bounds__(256) void moe_down(const short* __restrict__ Abase, const float* __restrict__ Wall,
                                                const float* __restrict__ Sd, float* __restrict__ Cbase,
                                                const int4* __restrict__ tilemap, int K, int N) {
    int4 tm = tilemap[blockIdx.y];
    int nrows = tm.z;
    if (nrows == 0) return;
    const short* A = Abase + (size_t)tm.y * K;
    float* C = Cbase + (size_t)tm.y * N;
    const float* B = (tm.x < 8) ? Wall + (size_t)tm.x * K * N : Sd;

    alignas(16) __shared__ short As[128][72];
    alignas(16) __shared__ short Bs[64][72];
    const int tid = threadIdx.x;
    const int lane = tid & 63, wid = tid >> 6;
    const int g = lane >> 4, li = lane & 15;
    const int wm = wid >> 1, wn = wid & 1;
    const int col0 = blockIdx.x * 64;

    f32x4 acc[4][2];
#pragma unroll
    for (int mi = 0; mi < 4; mi++)
#pragma unroll
        for (int ni = 0; ni < 2; ni++)
#pragma unroll
            for (int r = 0; r < 4; r++) acc[mi][ni][r] = 0.f;

    const int skb = (tid >> 4) << 2, snb = (tid & 15) << 2;

    for (int k0 = 0; k0 < K; k0 += 64) {
#pragma unroll
        for (int i = 0; i < 4; i++) {
            int cid = i * 256 + tid;
            int r = cid >> 3, c = cid & 7;
            s16x8 v;
            if (r < nrows) v = *(const s16x8*)&A[(size_t)r * K + k0 + c * 8];
            else {
#pragma unroll
                for (int j = 0; j < 8; j++) v[j] = 0;
            }
            *(s16x8*)&As[r][c * 8] = v;
        }
        {
            float4 r4[4];
#pragma unroll
            for (int kk = 0; kk < 4; kk++)
                r4[kk] = *(const float4*)(B + (size_t)(k0 + skb + kk) * N + col0 + snb);
#pragma unroll
            for (int n = 0; n < 4; n++) {
                s16x4 w;
                w[0] = f2bf((&r4[0].x)[n]); w[1] = f2bf((&r4[1].x)[n]);
                w[2] = f2bf((&r4[2].x)[n]); w[3] = f2bf((&r4[3].x)[n]);
                *(s16x4*)&Bs[snb + n][skb] = w;
            }
        }
        __syncthreads();
#pragma unroll
        for (int kk = 0; kk < 64; kk += 32) {
            s16x8 a[4], b[2];
#pragma unroll
            for (int mi = 0; mi < 4; mi++) a[mi] = *(const s16x8*)&As[wm * 64 + mi * 16 + li][kk + g * 8];
#pragma unroll
            for (int ni = 0; ni < 2; ni++) b[ni] = *(const s16x8*)&Bs[wn * 32 + ni * 16 + li][kk + g * 8];
#pragma unroll
            for (int mi = 0; mi < 4; mi++)
#pragma unroll
                for (int ni = 0; ni < 2; ni++)
                    acc[mi][ni] = __builtin_amdgcn_mfma_f32_16x16x32_bf16(a[mi], b[ni], acc[mi][ni], 0, 0, 0);
        }
        __syncthreads();
    }
#pragma unroll
    for (int mi = 0; mi < 4; mi++)
#pragma unroll
        for (int ni = 0; ni < 2; ni++) {
            int gc = col0 + wn * 32 + ni * 16 + li;
#pragma unroll
            for (int r = 0; r < 4; r++) {
                int gr = wm * 64 + mi * 16 + g * 4 + r;
                if (gr < nrows) C[(size_t)gr * N + gc] = acc[mi][ni][r];
            }
        }
}

// ---------------- RoPE + build qf/kf/v as split planes ----------------
__global__ void prep_qkv_kernel(const float* __restrict__ q, const float* __restrict__ kva,
                                const float* __restrict__ kv, const int* __restrict__ positions,
                                short* __restrict__ qfh, short* __restrict__ qfl,
                                short* __restrict__ kfh, short* __restrict__ kfl,
                                short* __restrict__ vbh, short* __restrict__ vbl) {
    int t = blockIdx.x;
    __shared__ float cs[16], sn[16];
    if (threadIdx.x < 16) {
        float invf = powf(10000.f, -(float)(2 * threadIdx.x) / 32.f);
        float fr = (float)positions[t] * invf;
        cs[threadIdx.x] = cosf(fr);
        sn[threadIdx.x] = sinf(fr);
    }
    __syncthreads();
    for (int i = threadIdx.x; i < NH * QKD; i += blockDim.x) {
        int h = i / QKD, d = i % QKD;
        float val;
        if (d < 64) val = q[(size_t)t * 1536 + h * QKD + d];
        else {
            int r = d - 64, pr = r >> 1;
            float x1 = q[(size_t)t * 1536 + h * QKD + 64 + 2 * pr];
            float x2 = q[(size_t)t * 1536 + h * QKD + 64 + 2 * pr + 1];
            val = (r & 1) ? (x1 * sn[pr] + x2 * cs[pr]) : (x1 * cs[pr] - x2 * sn[pr]);
        }
        short hh = f2bf(val);
        qfh[(size_t)t * 1536 + i] = hh;
        qfl[(size_t)t * 1536 + i] = f2bf(val - bf2f(hh));
    }
    for (int i = threadIdx.x; i < NH * QKD; i += blockDim.x) {
        int h = i / QKD, d = i % QKD;
        float val;
        if (d < 64) val = kv[(size_t)t * 2048 + h * 128 + d];
        else {
            int r = d - 64, pr = r >> 1;
            float x1 = kva[(size_t)t * 288 + 256 + 2 * pr];
            float x2 = kva[(size_t)t * 288 + 256 + 2 * pr + 1];
            val = (r & 1) ? (x1 * sn[pr] + x2 * cs[pr]) : (x1 * cs[pr] - x2 * sn[pr]);
        }
        short hh = f2bf(val);
        kfh[(size_t)t * 1536 + i] = hh;
        kfl[(size_t)t * 1536 + i] = f2bf(val - bf2f(hh));
    }
    for (int i = threadIdx.x; i < NH * VD; i += blockDim.x) {
        int h = i / VD, d = i % VD;
        float val = kv[(size_t)t * 2048 + h * 128 + 64 + d];
        short hh = f2bf(val);
        vbh[(size_t)t * 1024 + i] = hh;
        vbl[(size_t)t * 1024 + i] = f2bf(val - bf2f(hh));
    }
}

// =====================================================================
// MFMA flash attention (verified; reads/writes bf16 planes)
// =====================================================================
__global__ __launch_bounds__(256) void attn_mfma_kernel(const short* __restrict__ qfh, const short* __restrict__ qfl,
                                                        const short* __restrict__ kfh, const short* __restrict__ kfl,
                                                        const short* __restrict__ vbh, const short* __restrict__ vbl,
                                                        short* __restrict__ obh, short* __restrict__ obl) {
    __shared__ short K_hi[64][104], K_lo[64][104];
    __shared__ short Vt_hi[64][72], Vt_lo[64][72];
    __shared__ short P_hi[4][16][72], P_lo[4][16][72];
    const int qt = blockIdx.x, h = blockIdx.y;
    const int tid = threadIdx.x, lane = tid & 63, w = tid >> 6;
    const int g = lane >> 4, li = lane & 15;

    s16x8 q_hi[3], q_lo[3];
    {
        const short* qb_h = qfh + (size_t)(qt * 64 + w * 16 + li) * 1536 + h * QKD;
        const short* qb_l = qfl + (size_t)(qt * 64 + w * 16 + li) * 1536 + h * QKD;
#pragma unroll
        for (int ks = 0; ks < 3; ks++) {
            q_hi[ks] = *(const s16x8*)(qb_h + ks * 32 + g * 8);
            q_lo[ks] = *(const s16x8*)(qb_l + ks * 32 + g * 8);
        }
    }

    f32x4 acc_o[4];
#pragma unroll
    for (int nc = 0; nc < 4; nc++)
#pragma unroll
        for (int r = 0; r < 4; r++) acc_o[nc][r] = 0.f;
    float m4[4] = {-1e30f, -1e30f, -1e30f, -1e30f};
    float l4[4] = {0.f, 0.f, 0.f, 0.f};
    const float scale = 0.102062072616f;

    for (int kt = 0; kt <= qt; kt++) {
#pragma unroll
        for (int it = 0; it < 3; it++) {
            int cid = it * 256 + tid;
            int key = cid / 12, c = cid % 12;
            *(s16x8*)&K_hi[key][c * 8] = *(const s16x8*)&kfh[(size_t)(kt * 64 + key) * 1536 + h * QKD + c * 8];
            *(s16x8*)&K_lo[key][c * 8] = *(const s16x8*)&kfl[(size_t)(kt * 64 + key) * 1536 + h * QKD + c * 8];
        }
#pragma unroll
        for (int it = 0; it < 2; it++) {
            int cid = it * 256 + tid;
            int key = cid >> 3, vc = cid & 7;
            s16x8 vh = *(const s16x8*)&vbh[(size_t)(kt * 64 + key) * 1024 + h * VD + vc * 8];
            s16x8 vl = *(const s16x8*)&vbl[(size_t)(kt * 64 + key) * 1024 + h * VD + vc * 8];
#pragma unroll
            for (int j = 0; j < 8; j++) {
                Vt_hi[vc * 8 + j][key] = vh[j];
                Vt_lo[vc * 8 + j][key] = vl[j];
            }
        }
        __syncthreads();

        f32x4 acc_s[4];
#pragma unroll
        for (int kc = 0; kc < 4; kc++)
#pragma unroll
            for (int r = 0; r < 4; r++) acc_s[kc][r] = 0.f;
#pragma unroll
        for (int ks = 0; ks < 3; ks++) {
#pragma unroll
            for (int kc = 0; kc < 4; kc++) {
                s16x8 kh = *(const s16x8*)&K_hi[kc * 16 + li][ks * 32 + g * 8];
                s16x8 kl = *(const s16x8*)&K_lo[kc * 16 + li][ks * 32 + g * 8];
                acc_s[kc] = __builtin_amdgcn_mfma_f32_16x16x32_bf16(q_hi[ks], kh, acc_s[kc], 0, 0, 0);
                acc_s[kc] = __builtin_amdgcn_mfma_f32_16x16x32_bf16(q_lo[ks], kh, acc_s[kc], 0, 0, 0);
                acc_s[kc] = __builtin_amdgcn_mfma_f32_16x16x32_bf16(q_hi[ks], kl, acc_s[kc], 0, 0, 0);
            }
        }
#pragma unroll
        for (int kc = 0; kc < 4; kc++)
#pragma unroll
            for (int r = 0; r < 4; r++) acc_s[kc][r] *= scale;
        if (kt == qt) {
#pragma unroll
            for (int kc = 0; kc < 4; kc++) {
                int key = kt * 64 + kc * 16 + li;
#pragma unroll
                for (int r = 0; r < 4; r++) {
                    int qr = qt * 64 + w * 16 + g * 4 + r;
                    if (key > qr) acc_s[kc][r] = -1e30f;
                }
            }
        }
        float tm4[4];
#pragma unroll
        for (int r = 0; r < 4; r++)
            tm4[r] = fmaxf(fmaxf(acc_s[0][r], acc_s[1][r]), fmaxf(acc_s[2][r], acc_s[3][r]));
#pragma unroll
        for (int off = 1; off < 16; off <<= 1)
#pragma unroll
            for (int r = 0; r < 4; r++) tm4[r] = fmaxf(tm4[r], __shfl_xor(tm4[r], off));
        float alpha[4];
#pragma unroll
        for (int r = 0; r < 4; r++) {
            float mn = fmaxf(m4[r], tm4[r]);
            alpha[r] = __expf(m4[r] - mn);
            m4[r] = mn;
        }
        float rs[4] = {0.f, 0.f, 0.f, 0.f};
#pragma unroll
        for (int kc = 0; kc < 4; kc++)
#pragma unroll
            for (int r = 0; r < 4; r++) {
                float p = __expf(acc_s[kc][r] - m4[r]);
                rs[r] += p;
                short hh = f2bf(p);
                P_hi[w][g * 4 + r][kc * 16 + li] = hh;
                P_lo[w][g * 4 + r][kc * 16 + li] = f2bf(p - bf2f(hh));
            }
#pragma unroll
        for (int off = 1; off < 16; off <<= 1)
#pragma unroll
            for (int r = 0; r < 4; r++) rs[r] += __shfl_xor(rs[r], off);
#pragma unroll
        for (int r = 0; r < 4; r++) l4[r] = l4[r] * alpha[r] + rs[r];
#pragma unroll
        for (int nc = 0; nc < 4; nc++)
#pragma unroll
            for (int r = 0; r < 4; r++) acc_o[nc][r] *= alpha[r];
#pragma unroll
        for (int ks = 0; ks < 2; ks++) {
            s16x8 ph = *(const s16x8*)&P_hi[w][li][ks * 32 + g * 8];
            s16x8 pl = *(const s16x8*)&P_lo[w][li][ks * 32 + g * 8];
#pragma unroll
            for (int nc = 0; nc < 4; nc++) {
                s16x8 vh = *(const s16x8*)&Vt_hi[nc * 16 + li][ks * 32 + g * 8];
                s16x8 vl = *(const s16x8*)&Vt_lo[nc * 16 + li][ks * 32 + g * 8];
                acc_o[nc] = __builtin_amdgcn_mfma_f32_16x16x32_bf16(ph, vh, acc_o[nc], 0, 0, 0);
                acc_o[nc] = __builtin_amdgcn_mfma_f32_16x16x32_bf16(pl, vh, acc_o[nc], 0, 0, 0);
                acc_o[nc] = __builtin_amdgcn_mfma_f32_16x16x32_bf16(ph, vl, acc_o[nc], 0, 0, 0);
            }
        }
        __syncthreads();
    }
    float inv[4];
#pragma unroll
    for (int r = 0; r < 4; r++) inv[r] = 1.f / l4[r];
#pragma unroll
    for (int nc = 0; nc < 4; nc++)
#pragma unroll
        for (int r = 0; r < 4; r++) {
            float o = acc_o[nc][r] * inv[r];
            size_t idx = (size_t)(qt * 64 + w * 16 + g * 4 + r) * 1024 + h * VD + nc * 16 + li;
            short hh = f2bf(o);
            obh[idx] = hh;
            obl[idx] = f2bf(o - bf2f(hh));
        }
}

// ---------------- fused resid-add + post-rmsnorm + routing ----------------
__global__ __launch_bounds__(256) void fused_post_attn(float* __restrict__ x0, const float* __restrict__ att,
                                                       const float* __restrict__ w, const float* __restrict__ gate_w,
                                                       const float* __restrict__ gate_bias,
                                                       short* __restrict__ h2bf, int* __restrict__ topidx,
                                                       float* __restrict__ topw) {
    int t = blockIdx.x;
    float resid[8];
    float ss = 0.f;
#pragma unroll
    for (int j = 0; j < 8; j++) {
        int i = threadIdx.x + j * 256;
        float v = x0[(size_t)t * HDIM + i] + att[(size_t)t * HDIM + i];
        resid[j] = v;
        x0[(size_t)t * HDIM + i] = v;
        ss += v * v;
    }
    float r = rsqrtf(block_sum(ss) / HDIM + EPSF);
    float acc[8] = {0.f, 0.f, 0.f, 0.f, 0.f, 0.f, 0.f, 0.f};
#pragma unroll
    for (int j = 0; j < 8; j++) {
        int i = threadIdx.x + j * 256;
        float v = resid[j] * r * w[i];
        h2bf[(size_t)t * HDIM + i] = f2bf(v);
        const float* gw = gate_w + (size_t)i * 8;
        float4 g0 = *(const float4*)gw;
        float4 g1 = *(const float4*)(gw + 4);
        acc[0] = fmaf(v, g0.x, acc[0]); acc[1] = fmaf(v, g0.y, acc[1]);
        acc[2] = fmaf(v, g0.z, acc[2]); acc[3] = fmaf(v, g0.w, acc[3]);
        acc[4] = fmaf(v, g1.x, acc[4]); acc[5] = fmaf(v, g1.y, acc[5]);
        acc[6] = fmaf(v, g1.z, acc[6]); acc[7] = fmaf(v, g1.w, acc[7]);
    }
    __shared__ float logits[8];
    for (int e = 0; e < 8; e++) {
        float s = block_sum(acc[e]);
        if (threadIdx.x == 0) logits[e] = s;
    }
    __syncthreads();
    if (threadIdx.x == 0) {
        float sig[8], sc[8];
        for (int e = 0; e < 8; e++) {
            sig[e] = 1.f / (1.f + expf(-logits[e]));
            sc[e] = sig[e] + gate_bias[e];
        }
        int i0 = 0;
        for (int e = 1; e < 8; e++) if (sc[e] > sc[i0]) i0 = e;
        int i1 = -1;
        for (int e = 0; e < 8; e++) if (e != i0 && (i1 < 0 || sc[e] > sc[i1])) i1 = e;
        float w0 = sig[i0], w1 = sig[i1], s = w0 + w1 + 1e-20f;
        topidx[t * 2 + 0] = i0; topidx[t * 2 + 1] = i1;
        topw[t * 2 + 0] = w0 / s; topw[t * 2 + 1] = w1 / s;
    }
}

// ---------------- counting sort + tile map (+8 shared tiles) ----------------
__global__ void sort_kernel(const int* __restrict__ topidx, int* __restrict__ sorted_t,
                            int* __restrict__ slotpos, int4* __restrict__ tilemap) {
    __shared__ int counts[8], offs[9];
    int wid = threadIdx.x >> 6, lane = threadIdx.x & 63;
    int cnt = 0;
    for (int base = 0; base < 2 * T_; base += 64) {
        int e = topidx[base + lane];
        unsigned long long m = __ballot(e == wid);
        cnt += __popcll(m);
    }
    if (lane == 0) counts[wid] = cnt;
    __syncthreads();
    if (threadIdx.x == 0) {
        offs[0] = 0;
        for (int e = 0; e < 8; e++) offs[e + 1] = offs[e] + counts[e];
    }
    __syncthreads();
    int pos = offs[wid];
    for (int base = 0; base < 2 * T_; base += 64) {
        int sl = base + lane;
        int e = topidx[sl];
        bool match = (e == wid);
        unsigned long long m = __ballot(match);
        if (match) {
            int before = __popcll(m & ((1ull << lane) - 1ull));
            int pp = pos + before;
            sorted_t[pp] = sl >> 1;
            slotpos[sl] = pp;
        }
        pos += __popcll(m);
    }
    __syncthreads();
    if (threadIdx.x == 0) {
        int nt = 0;
        for (int e = 0; e < 8; e++) {
            int c = counts[e], o = offs[e];
            for (int r = 0; r < c; r += 128) {
                tilemap[nt] = make_int4(e, o + r, min(128, c - r), 0);
                nt++;
            }
        }
        for (int r = 0; r < 8; r++) {             // shared MLP as expert 8
            tilemap[nt] = make_int4(8, 2048 + r * 128, 128, 0);
            nt++;
        }
        for (int i = nt; i < MAXTILES; i++) tilemap[i] = make_int4(0, 0, 0, 0);
    }
}

// ---------------- gather h2bf rows (slots 2048+ are identity tokens) ----------------
__global__ void gather_bf16_kernel(const short* __restrict__ h2bf, const int* __restrict__ sorted_t,
                                   short* __restrict__ gout) {
    int pp = blockIdx.x;
    int t = (pp < 2048) ? sorted_t[pp] : (pp - 2048);
    const s16x8* src = (const s16x8*)(h2bf + (size_t)t * HDIM);
    s16x8* dst = (s16x8*)(gout + (size_t)pp * HDIM);
    dst[threadIdx.x] = src[threadIdx.x];
}

// ---------------- final combine -> f32 out ----------------
__global__ void final_kernel(const float* __restrict__ resid, const float* __restrict__ md,
                             const int* __restrict__ slotpos, const float* __restrict__ topw,
                             float* __restrict__ out) {
    int t = blockIdx.x;
    int p0 = slotpos[t * 2 + 0], p1 = slotpos[t * 2 + 1];
    float w0 = topw[t * 2 + 0] * 2.5f, w1 = topw[t * 2 + 1] * 2.5f;
    const float* mds = md + (size_t)(2048 + t) * HDIM;
    for (int c = threadIdx.x; c < HDIM; c += blockDim.x) {
        float v = resid[(size_t)t * HDIM + c] + mds[c]
                + w0 * md[(size_t)p0 * HDIM + c] + w1 * md[(size_t)p1 * HDIM + c];
        out[(size_t)t * HDIM + c] = v;
    }
}

// ---------------- launcher ----------------
extern "C" void kernel_launch(void* const* d_in, const int* in_sizes, int n_in,
                              void* d_out, int out_size, void* d_ws, size_t ws_size,
                              hipStream_t stream) {
    (void)in_sizes; (void)n_in; (void)out_size; (void)ws_size;
    const int*   input_ids = (const int*)d_in[0];
    const int*   positions = (const int*)d_in[1];
    const float* prev      = (const float*)d_in[2];
    const float* embed     = (const float*)d_in[3];
    const float* enorm_w   = (const float*)d_in[4];
    const float* hnorm_w   = (const float*)d_in[5];
    const float* eh_proj_w = (const float*)d_in[6];
    const float* in_ln_w   = (const float*)d_in[7];
    const float* post_ln_w = (const float*)d_in[8];
    const float* q_a_w     = (const float*)d_in[9];
    const float* q_a_ln_w  = (const float*)d_in[10];
    const float* q_b_w     = (const float*)d_in[11];
    const float* kv_a_w    = (const float*)d_in[12];
    const float* kv_a_ln_w = (const float*)d_in[13];
    const float* kv_b_w    = (const float*)d_in[14];
    const float* o_w       = (const float*)d_in[15];
    const float* gate_w    = (const float*)d_in[16];
    const float* gate_bias = (const float*)d_in[17];
    const float* exp_g     = (const float*)d_in[18];
    const float* exp_u     = (const float*)d_in[19];
    const float* exp_d     = (const float*)d_in[20];
    const float* sh_g      = (const float*)d_in[21];
    const float* sh_u      = (const float*)d_in[22];
    const float* sh_d      = (const float*)d_in[23];
    float* out = (float*)d_out;

    float* ws = (float*)d_ws;
    short* catH  = (short*)(ws + OF_CATH);
    short* catL  = (short*)(ws + OF_CATL);
    short* gact  = (short*)(ws + OF_GACT);
    float* x0    = ws + OF_X0;
    short* mact  = (short*)(ws + OF_MACT);
    short* hH    = (short*)(ws + OF_HH);
    short* hL    = (short*)(ws + OF_HL);
    float* qraw  = ws + OF_QRAW;
    float* qbuf  = ws + OF_QBUF;
    float* kva   = ws + OF_KVA;
    float* kvbuf = ws + OF_KVBUF;
    short* qaH   = (short*)(ws + OF_QAH);
    short* qaL   = (short*)(ws + OF_QAL);
    short* kvcnH = (short*)(ws + OF_KVCNH);
    short* kvcnL = (short*)(ws + OF_KVCNL);
    short* qfH   = (short*)(ws + OF_QFH);
    short* qfL   = (short*)(ws + OF_QFL);
    short* kfH   = (short*)(ws + OF_KFH);
    short* kfL   = (short*)(ws + OF_KFL);
    short* vbH   = (short*)(ws + OF_VBH);
    short* vbL   = (short*)(ws + OF_VBL);
    short* obH   = (short*)(ws + OF_OBH);
    short* obL   = (short*)(ws + OF_OBL);
    float* att   = ws + OF_ATT;
    short* h2bf  = (short*)(ws + OF_H2BF);
    float* md    = ws + OF_MD;
    int*   ri       = (int*)(ws + OF_ROUT);
    int*   topidx   = ri;
    int*   sorted_t = ri + 2048;
    int*   slotpos  = ri + 4096;
    int4*  tilemap  = (int4*)(ri + 6144);
    float* topw     = (float*)(ri + 6144 + 4 * MAXTILES);
    short* ehTH  = (short*)(ws + OF_EHTH);
    short* ehTL  = (short*)(ws + OF_EHTL);
    short* qaTH  = (short*)(ws + OF_QATH);
    short* qaTL  = (short*)(ws + OF_QATL);
    short* qbTH  = (short*)(ws + OF_QBTH);
    short* qbTL  = (short*)(ws + OF_QBTL);
    short* kvaTH = (short*)(ws + OF_KVATH);
    short* kvaTL = (short*)(ws + OF_KVATL);
    short* kvbTH = (short*)(ws + OF_KVBTH);
    short* kvbTL = (short*)(ws + OF_KVBTL);
    short* owTH  = (short*)(ws + OF_OWTH);
    short* owTL  = (short*)(ws + OF_OWTL);

    dim3 blk(256);

    // 0. weight transpose+split (shared MLP weights no longer need planes)
    transpose_split_kernel<<<dim3(64, 32), blk, 0, stream>>>(eh_proj_w, ehTH, ehTL, 4096, 2048, 1);
    transpose_split_kernel<<<dim3(32, 8), blk, 0, stream>>>(q_a_w, qaTH, qaTL, 2048, 512, 1);
    transpose_split_kernel<<<dim3(8, 24), blk, 0, stream>>>(q_b_w, qbTH, qbTL, 512, 1536, 1);
    transpose_split_kernel<<<dim3(32, 5), blk, 0, stream>>>(kv_a_w, kvaTH, kvaTL, 2048, 288, 1);
    transpose_split_kernel<<<dim3(4, 32), blk, 0, stream>>>(kv_b_w, kvbTH, kvbTL, 256, 2048, 1);
    transpose_split_kernel<<<dim3(16, 32), blk, 0, stream>>>(o_w, owTH, owTL, 1024, 2048, 1);

    // 1. embed + rmsnorm + concat
    embed_cat_kernel<<<T_, blk, 0, stream>>>(input_ids, embed, enorm_w, prev, hnorm_w, catH, catL);
    // 2. x0 = cat @ eh_proj
    gemm_planes<true><<<dim3(32, 8), blk, 0, stream>>>(catH, catL, ehTH, ehTL, x0, T_, 2048, 4096);
    // 3. h = rmsnorm(x0)
    rmsnorm_kernel<<<T_, blk, 0, stream>>>(x0, 2048, 2048, in_ln_w, nullptr, hH, hL, 2048);
    // 4. q_a
    gemm_planes<true><<<dim3(8, 8), blk, 0, stream>>>(hH, hL, qaTH, qaTL, qraw, T_, 512, 2048);
    rmsnorm_kernel<<<T_, blk, 0, stream>>>(qraw, 512, 512, q_a_ln_w, nullptr, qaH, qaL, 512);
    // 5. q = qa @ q_b
    gemm_planes<true><<<dim3(24, 8), blk, 0, stream>>>(qaH, qaL, qbTH, qbTL, qbuf, T_, 1536, 512);
    // 6. kva = h @ kv_a
    gemm_planes<true><<<dim3(5, 8), blk, 0, stream>>>(hH, hL, kvaTH, kvaTL, kva, T_, 288, 2048);
    // 7. kvcn
    rmsnorm_kernel<<<T_, blk, 0, stream>>>(kva, 288, 256, kv_a_ln_w, nullptr, kvcnH, kvcnL, 256);
    // 8. kv = kvcn @ kv_b
    gemm_planes<true><<<dim3(32, 8), blk, 0, stream>>>(kvcnH, kvcnL, kvbTH, kvbTL, kvbuf, T_, 2048, 256);
    // 9. rope + planes
    prep_qkv_kernel<<<T_, blk, 0, stream>>>(qbuf, kva, kvbuf, positions, qfH, qfL, kfH, kfL, vbH, vbL);
    // 10. flash attention
    attn_mfma_kernel<<<dim3(T_ / 64, NH), blk, 0, stream>>>(qfH, qfL, kfH, kfL, vbH, vbL, obH, obL);
    // 11. attn_out = ob @ o_w
    gemm_planes<true><<<dim3(32, 8), blk, 0, stream>>>(obH, obL, owTH, owTL, att, T_, 2048, 1024);
    // 12-14. fused resid + rmsnorm + routing
    fused_post_attn<<<T_, blk, 0, stream>>>(x0, att, post_ln_w, gate_w, gate_bias, h2bf, topidx, topw);
    // 15. sort (+shared tiles)
    sort_kernel<<<1, 512, 0, stream>>>(topidx, sorted_t, slotpos, tilemap);
    // 16. gather (bf16; slots 2048+ identity)
    gather_bf16_kernel<<<3 * T_, blk, 0, stream>>>(h2bf, sorted_t, gact);
    // 17+18. MoE gate+up fused with silu -> mact (experts + shared)
    moe_gateup<<<dim3(16, MAXTILES), blk, 0, stream>>>(gact, exp_g, exp_u, sh_g, sh_u, mact, tilemap, 2048, 1024);
    // 19. MoE down (experts + shared)
    moe_down<<<dim3(32, MAXTILES), blk, 0, stream>>>(mact, exp_d, sh_d, md, tilemap, 1024, 2048);
    // 20. final combine (shared = md slot 2048+t)
    final_kernel<<<T_, blk, 0, stream>>>(x0, md, slotpos, topw, out);
}